// Round 8
// baseline (310.368 us; speedup 1.0000x reference)
//
#include <hip/hip_runtime.h>
#include <hip/hip_bf16.h>

typedef __attribute__((ext_vector_type(8))) short bf16x8;
typedef __attribute__((ext_vector_type(4))) float f32x4;

__device__ __forceinline__ short to_bf16s(float f) {
    union { __hip_bfloat16 h; short s; } u;
    u.h = __float2bfloat16(f);
    return u.s;
}

__device__ __forceinline__ void load_lds16(const void* g, void* l) {
    __builtin_amdgcn_global_load_lds((const __attribute__((address_space(1))) void*)g,
                                     (__attribute__((address_space(3))) void*)l, 16, 0, 0);
}

// ---------------------------------------------------------------------------
// prep: blocks [0,10240): weight transposes (fp32 [K][N] -> bf16 [N][K]),
// W1/W3 column-interleaved into W13T[4096][1024].  Blocks [10240,18432):
// rmsnorm1 row (bid-10240) -> xn1 bf16.
// ---------------------------------------------------------------------------
__global__ __launch_bounds__(256)
void prep_kernel(const float* __restrict__ Wq, const float* __restrict__ Wk,
                 const float* __restrict__ Wv, const float* __restrict__ Wo,
                 const float* __restrict__ W1, const float* __restrict__ W3,
                 const float* __restrict__ W2,
                 short* __restrict__ WqT, short* __restrict__ WkT,
                 short* __restrict__ WvT, short* __restrict__ WoT,
                 short* __restrict__ W13T, short* __restrict__ W2T,
                 const float* __restrict__ x, const float* __restrict__ n1w,
                 short* __restrict__ xn1) {
    const int bid = blockIdx.x;
    const int t = threadIdx.x;
    if (bid >= 10240) {
        const long row = bid - 10240;
        float4 v = ((const float4*)(x + row * 1024))[t];
        float ss = v.x * v.x + v.y * v.y + v.z * v.z + v.w * v.w;
        #pragma unroll
        for (int off = 32; off; off >>= 1) ss += __shfl_xor(ss, off);
        __shared__ float red[4];
        if ((t & 63) == 0) red[t >> 6] = ss;
        __syncthreads();
        ss = red[0] + red[1] + red[2] + red[3];
        const float inv = rsqrtf(ss * (1.0f / 1024.0f) + 1e-6f);
        float4 wv = ((const float4*)n1w)[t];
        short4 o;
        o.x = to_bf16s(v.x * inv * wv.x);
        o.y = to_bf16s(v.y * inv * wv.y);
        o.z = to_bf16s(v.z * inv * wv.z);
        o.w = to_bf16s(v.w * inv * wv.w);
        *(short4*)&xn1[row * 1024 + t * 4] = o;
        return;
    }
    __shared__ float tile[32][33];
    const float* src; short* dst; int K, N, tl, rs = 1, ro = 0;
    if (bid < 4096) {
        const int wi = bid >> 10; tl = bid & 1023;
        src = wi == 0 ? Wq : wi == 1 ? Wk : wi == 2 ? Wv : Wo;
        dst = wi == 0 ? WqT : wi == 1 ? WkT : wi == 2 ? WvT : WoT;
        K = 1024; N = 1024;
    } else if (bid < 8192) {
        const int wi = (bid - 4096) >> 11; tl = (bid - 4096) & 2047;
        src = wi ? W3 : W1; dst = W13T; rs = 2; ro = wi;
        K = 1024; N = 2048;
    } else {
        tl = bid - 8192; src = W2; dst = W2T;
        K = 2048; N = 1024;
    }
    const int nx = N >> 5;
    const int n0 = (tl % nx) * 32, k0 = (tl / nx) * 32;
    {
        const int lr = t >> 3, lc = (t & 7) * 4;
        float4 v = *(const float4*)&src[(long)(k0 + lr) * N + n0 + lc];
        tile[lr][lc] = v.x; tile[lr][lc + 1] = v.y;
        tile[lr][lc + 2] = v.z; tile[lr][lc + 3] = v.w;
    }
    __syncthreads();
    {
        const int nr = t >> 3, kc = (t & 7) * 4;
        short4 o;
        o.x = to_bf16s(tile[kc][nr]);
        o.y = to_bf16s(tile[kc + 1][nr]);
        o.z = to_bf16s(tile[kc + 2][nr]);
        o.w = to_bf16s(tile[kc + 3][nr]);
        *(short4*)&dst[(long)((n0 + nr) * rs + ro) * K + k0 + kc] = o;
    }
}

// ---------------------------------------------------------------------------
// RMSNorm (fp32 in) -> bf16 out.  One block per row, D=1024.  (norm2)
// ---------------------------------------------------------------------------
__global__ __launch_bounds__(256)
void rmsnorm_kernel(const float* __restrict__ x, const float* __restrict__ wt,
                    short* __restrict__ out) {
    const long row = blockIdx.x;
    const int t = threadIdx.x;
    float4 v = ((const float4*)(x + row * 1024))[t];
    float ss = v.x * v.x + v.y * v.y + v.z * v.z + v.w * v.w;
    #pragma unroll
    for (int off = 32; off; off >>= 1) ss += __shfl_xor(ss, off);
    __shared__ float red[4];
    if ((t & 63) == 0) red[t >> 6] = ss;
    __syncthreads();
    ss = red[0] + red[1] + red[2] + red[3];
    const float inv = rsqrtf(ss * (1.0f / 1024.0f) + 1e-6f);
    float4 wv = ((const float4*)wt)[t];
    short4 o;
    o.x = to_bf16s(v.x * inv * wv.x);
    o.y = to_bf16s(v.y * inv * wv.y);
    o.z = to_bf16s(v.z * inv * wv.z);
    o.w = to_bf16s(v.w * inv * wv.w);
    *(short4*)&out[row * 1024 + t * 4] = o;
}

// ===========================================================================
// Single-barrier-per-K-tile GEMM template family (T3-minimal):
//   per kt: {ds_read frags ; issue stage(kt+1) ; lgkm ; MFMA cluster(s) ;
//            vmcnt(0) [loads issued a full cluster earlier] ; s_barrier}
// Buffer safety: reads target buf=kt&1, writes target buf^1; each wave's own
// vmcnt(0) before the barrier makes DMA writes visible to all at barrier exit.
// T2 XOR-swizzle via inverse-swizzled global source + swizzled ds_read.
// T1 bijective XCD chunk swizzle (all grids % 8 == 0).
// ===========================================================================

// ---------------------------------------------------------------------------
// gemm192qkv: 256x192 tile, BK=64, 8 waves (2 wr x 4 wc) of 128x48.
// Grid 512 = 2 exact rounds.  48 MFMA / barrier.  QKV split epilogue.
// ---------------------------------------------------------------------------
__global__ __launch_bounds__(512, 2)
void gemm192qkv(const short* __restrict__ A, const short* __restrict__ B0,
                short* __restrict__ outp, short* __restrict__ outp2,
                int M, int N, int K) {
    __shared__ __align__(16) char lds[114688];   // A: 2x32K @0, B: 2x24K @65536

    const int t = threadIdx.x;
    const int lane = t & 63, w = t >> 6;
    const int wr = w >> 2, wc = w & 3;
    const int lm = lane & 15, lk = lane >> 4;
    const int sw = (lm & 7) << 4;

    const int nbn = N / 192;                     // 16
    const int chunk = gridDim.x >> 3;
    const int logical = (blockIdx.x & 7) * chunk + (blockIdx.x >> 3);
    const int bm = logical / nbn, bn = logical - (logical / nbn) * nbn;

    const long Kb = (long)K * 2;
    const char* Ab = (const char*)A;
    const char* Bb = (const char*)B0;

    long srcA[4], srcB[3];
    {
        const int rowp = t >> 3;
        const int cbx = (t & 7) * 16;
        const int swz = ((t >> 3) & 7) << 4;
        #pragma unroll
        for (int c = 0; c < 4; ++c)
            srcA[c] = (long)(bm * 256 + c * 64 + rowp) * Kb + (cbx ^ swz);
        #pragma unroll
        for (int c = 0; c < 3; ++c)
            srcB[c] = (long)(bn * 192 + c * 64 + rowp) * Kb + (cbx ^ swz);
    }
    auto stage = [&](int kt) {
        const int buf = kt & 1;
        #pragma unroll
        for (int c = 0; c < 4; ++c)
            load_lds16(Ab + srcA[c] + (long)kt * 128, &lds[buf * 32768 + c * 8192 + t * 16]);
        #pragma unroll
        for (int c = 0; c < 3; ++c)
            load_lds16(Bb + srcB[c] + (long)kt * 128, &lds[65536 + buf * 24576 + c * 8192 + t * 16]);
    };

    f32x4 acc[8][3] = {};
    bf16x8 a[4][2], b[3][2];
    const int nt = K >> 6;

    stage(0);
    asm volatile("s_waitcnt vmcnt(0)" ::: "memory");
    __builtin_amdgcn_s_barrier();

    for (int kt = 0; kt < nt; ++kt) {
        const int buf = kt & 1;
        const bool pf = kt + 1 < nt;
        // B (all 3 n-frags) + A m-group 0
        #pragma unroll
        for (int n_ = 0; n_ < 3; ++n_) {
            const int rb = 65536 + buf * 24576 + (wc * 48 + n_ * 16 + lm) * 128;
            b[n_][0] = *(const bf16x8*)&lds[rb + ((lk * 16) ^ sw)];
            b[n_][1] = *(const bf16x8*)&lds[rb + ((64 + lk * 16) ^ sw)];
        }
        #pragma unroll
        for (int m_ = 0; m_ < 4; ++m_) {
            const int rb = buf * 32768 + (wr * 128 + m_ * 16 + lm) * 128;
            a[m_][0] = *(const bf16x8*)&lds[rb + ((lk * 16) ^ sw)];
            a[m_][1] = *(const bf16x8*)&lds[rb + ((64 + lk * 16) ^ sw)];
        }
        if (pf) stage(kt + 1);
        asm volatile("s_waitcnt lgkmcnt(0)");
        __builtin_amdgcn_s_setprio(1);
        #pragma unroll
        for (int m_ = 0; m_ < 4; ++m_)
            #pragma unroll
            for (int n_ = 0; n_ < 3; ++n_) {
                acc[m_][n_] = __builtin_amdgcn_mfma_f32_16x16x32_bf16(a[m_][0], b[n_][0], acc[m_][n_], 0, 0, 0);
                acc[m_][n_] = __builtin_amdgcn_mfma_f32_16x16x32_bf16(a[m_][1], b[n_][1], acc[m_][n_], 0, 0, 0);
            }
        // A m-group 1
        #pragma unroll
        for (int m_ = 0; m_ < 4; ++m_) {
            const int rb = buf * 32768 + (wr * 128 + 64 + m_ * 16 + lm) * 128;
            a[m_][0] = *(const bf16x8*)&lds[rb + ((lk * 16) ^ sw)];
            a[m_][1] = *(const bf16x8*)&lds[rb + ((64 + lk * 16) ^ sw)];
        }
        asm volatile("s_waitcnt lgkmcnt(0)");
        #pragma unroll
        for (int m_ = 0; m_ < 4; ++m_)
            #pragma unroll
            for (int n_ = 0; n_ < 3; ++n_) {
                acc[4 + m_][n_] = __builtin_amdgcn_mfma_f32_16x16x32_bf16(a[m_][0], b[n_][0], acc[4 + m_][n_], 0, 0, 0);
                acc[4 + m_][n_] = __builtin_amdgcn_mfma_f32_16x16x32_bf16(a[m_][1], b[n_][1], acc[4 + m_][n_], 0, 0, 0);
            }
        __builtin_amdgcn_s_setprio(0);
        if (pf) asm volatile("s_waitcnt vmcnt(0)" ::: "memory");
        __builtin_amdgcn_s_barrier();
    }

    #pragma unroll
    for (int mf = 0; mf < 8; ++mf)
      #pragma unroll
      for (int nf = 0; nf < 3; ++nf)
        #pragma unroll
        for (int r = 0; r < 4; ++r) {
            const int grow = bm * 256 + wr * 128 + mf * 16 + lk * 4 + r;
            const int gcol = bn * 192 + wc * 48 + nf * 16 + lm;
            const float v = acc[mf][nf][r];
            if (gcol < 2048)
                outp[(long)grow * 2048 + gcol] = to_bf16s(v);
            else
                outp2[(long)(gcol - 2048) * 8192 + grow] = to_bf16s(v);
        }
}

// ---------------------------------------------------------------------------
// gemm256fv2: 256x256 tile, BK=64, 8 waves (2x4) of 128x64.  Grid 512 =
// 2 rounds.  64 MFMA / barrier (2 clusters of 32).  Fused SwiGLU epilogue
// over column-interleaved B: h[row][gcol/2] = silu(C_even)*C_odd.
// ---------------------------------------------------------------------------
__global__ __launch_bounds__(512, 2)
void gemm256fv2(const short* __restrict__ A, const short* __restrict__ B0,
                short* __restrict__ outp, int M, int N, int K) {
    __shared__ __align__(16) char lds[131072];   // A: 2x32K @0, B: 2x32K @65536

    const int t = threadIdx.x;
    const int lane = t & 63, w = t >> 6;
    const int wr = w >> 2, wc = w & 3;
    const int lm = lane & 15, lk = lane >> 4;
    const int sw = (lm & 7) << 4;

    const int nbn = N >> 8;                      // 16
    const int chunk = gridDim.x >> 3;
    const int logical = (blockIdx.x & 7) * chunk + (blockIdx.x >> 3);
    const int bm = logical / nbn, bn = logical - (logical / nbn) * nbn;

    const long Kb = (long)K * 2;
    const char* Ab = (const char*)A;
    const char* Bb = (const char*)B0;

    long srcA[4], srcB[4];
    {
        const int rowp = t >> 3;
        const int cbx = (t & 7) * 16;
        const int swz = ((t >> 3) & 7) << 4;
        #pragma unroll
        for (int c = 0; c < 4; ++c) {
            srcA[c] = (long)(bm * 256 + c * 64 + rowp) * Kb + (cbx ^ swz);
            srcB[c] = (long)(bn * 256 + c * 64 + rowp) * Kb + (cbx ^ swz);
        }
    }
    auto stage = [&](int kt) {
        const int buf = kt & 1;
        #pragma unroll
        for (int c = 0; c < 4; ++c)
            load_lds16(Ab + srcA[c] + (long)kt * 128, &lds[buf * 32768 + c * 8192 + t * 16]);
        #pragma unroll
        for (int c = 0; c < 4; ++c)
            load_lds16(Bb + srcB[c] + (long)kt * 128, &lds[65536 + buf * 32768 + c * 8192 + t * 16]);
    };

    f32x4 acc[8][4] = {};
    bf16x8 a[4][2], b[4][2];
    const int nt = K >> 6;

    stage(0);
    asm volatile("s_waitcnt vmcnt(0)" ::: "memory");
    __builtin_amdgcn_s_barrier();

    for (int kt = 0; kt < nt; ++kt) {
        const int buf = kt & 1;
        const bool pf = kt + 1 < nt;
        #pragma unroll
        for (int n_ = 0; n_ < 4; ++n_) {
            const int rb = 65536 + buf * 32768 + (wc * 64 + n_ * 16 + lm) * 128;
            b[n_][0] = *(const bf16x8*)&lds[rb + ((lk * 16) ^ sw)];
            b[n_][1] = *(const bf16x8*)&lds[rb + ((64 + lk * 16) ^ sw)];
        }
        #pragma unroll
        for (int m_ = 0; m_ < 4; ++m_) {
            const int rb = buf * 32768 + (wr * 128 + m_ * 16 + lm) * 128;
            a[m_][0] = *(const bf16x8*)&lds[rb + ((lk * 16) ^ sw)];
            a[m_][1] = *(const bf16x8*)&lds[rb + ((64 + lk * 16) ^ sw)];
        }
        if (pf) stage(kt + 1);
        asm volatile("s_waitcnt lgkmcnt(0)");
        __builtin_amdgcn_s_setprio(1);
        #pragma unroll
        for (int m_ = 0; m_ < 4; ++m_)
            #pragma unroll
            for (int n_ = 0; n_ < 4; ++n_) {
                acc[m_][n_] = __builtin_amdgcn_mfma_f32_16x16x32_bf16(a[m_][0], b[n_][0], acc[m_][n_], 0, 0, 0);
                acc[m_][n_] = __builtin_amdgcn_mfma_f32_16x16x32_bf16(a[m_][1], b[n_][1], acc[m_][n_], 0, 0, 0);
            }
        #pragma unroll
        for (int m_ = 0; m_ < 4; ++m_) {
            const int rb = buf * 32768 + (wr * 128 + 64 + m_ * 16 + lm) * 128;
            a[m_][0] = *(const bf16x8*)&lds[rb + ((lk * 16) ^ sw)];
            a[m_][1] = *(const bf16x8*)&lds[rb + ((64 + lk * 16) ^ sw)];
        }
        asm volatile("s_waitcnt lgkmcnt(0)");
        #pragma unroll
        for (int m_ = 0; m_ < 4; ++m_)
            #pragma unroll
            for (int n_ = 0; n_ < 4; ++n_) {
                acc[4 + m_][n_] = __builtin_amdgcn_mfma_f32_16x16x32_bf16(a[m_][0], b[n_][0], acc[4 + m_][n_], 0, 0, 0);
                acc[4 + m_][n_] = __builtin_amdgcn_mfma_f32_16x16x32_bf16(a[m_][1], b[n_][1], acc[4 + m_][n_], 0, 0, 0);
            }
        __builtin_amdgcn_s_setprio(0);
        if (pf) asm volatile("s_waitcnt vmcnt(0)" ::: "memory");
        __builtin_amdgcn_s_barrier();
    }

    const int NH = N >> 1;
    #pragma unroll
    for (int mf = 0; mf < 8; ++mf)
      #pragma unroll
      for (int nf = 0; nf < 4; ++nf)
        #pragma unroll
        for (int r = 0; r < 4; ++r) {
            const int grow = bm * 256 + wr * 128 + mf * 16 + lk * 4 + r;
            const int gcol = bn * 256 + wc * 64 + nf * 16 + lm;
            const float v = acc[mf][nf][r];
            const float g3 = __shfl_xor(v, 1);
            if (!(lane & 1)) {
                const float sws = v / (1.f + __expf(-v));
                outp[(long)grow * NH + (gcol >> 1)] = to_bf16s(sws * g3);
            }
        }
}

// ---------------------------------------------------------------------------
// gemm128res: 256x128 tile, BK=64, 8 waves (4 wr x 2 wc) of 64x64.  Grid
// 256 = 1 round.  One 32-MFMA cluster per barrier.  out = res + C (fp32).
// ---------------------------------------------------------------------------
__global__ __launch_bounds__(512, 2)
void gemm128res(const short* __restrict__ A, const short* __restrict__ B0,
                const float* __restrict__ res, float* __restrict__ outp,
                int M, int N, int K) {
    __shared__ __align__(16) char lds[98304];    // A: 2x32K @0, B: 2x16K @65536

    const int t = threadIdx.x;
    const int lane = t & 63, w = t >> 6;
    const int wr = w >> 1, wc = w & 1;
    const int lm = lane & 15, lk = lane >> 4;
    const int sw = (lm & 7) << 4;

    const int nbn = N >> 7;                      // 8
    const int chunk = gridDim.x >> 3;
    const int logical = (blockIdx.x & 7) * chunk + (blockIdx.x >> 3);
    const int bm = logical / nbn, bn = logical - (logical / nbn) * nbn;

    const long Kb = (long)K * 2;
    const char* Ab = (const char*)A;
    const char* Bb = (const char*)B0;

    long srcA[4], srcB[2];
    {
        const int rowp = t >> 3;
        const int cbx = (t & 7) * 16;
        const int swz = ((t >> 3) & 7) << 4;
        #pragma unroll
        for (int c = 0; c < 4; ++c)
            srcA[c] = (long)(bm * 256 + c * 64 + rowp) * Kb + (cbx ^ swz);
        #pragma unroll
        for (int c = 0; c < 2; ++c)
            srcB[c] = (long)(bn * 128 + c * 64 + rowp) * Kb + (cbx ^ swz);
    }
    auto stage = [&](int kt) {
        const int buf = kt & 1;
        #pragma unroll
        for (int c = 0; c < 4; ++c)
            load_lds16(Ab + srcA[c] + (long)kt * 128, &lds[buf * 32768 + c * 8192 + t * 16]);
        #pragma unroll
        for (int c = 0; c < 2; ++c)
            load_lds16(Bb + srcB[c] + (long)kt * 128, &lds[65536 + buf * 16384 + c * 8192 + t * 16]);
    };

    f32x4 acc[4][4] = {};
    bf16x8 a[4][2], b[4][2];
    const int nt = K >> 6;

    stage(0);
    asm volatile("s_waitcnt vmcnt(0)" ::: "memory");
    __builtin_amdgcn_s_barrier();

    for (int kt = 0; kt < nt; ++kt) {
        const int buf = kt & 1;
        const bool pf = kt + 1 < nt;
        #pragma unroll
        for (int m_ = 0; m_ < 4; ++m_) {
            const int rb = buf * 32768 + (wr * 64 + m_ * 16 + lm) * 128;
            a[m_][0] = *(const bf16x8*)&lds[rb + ((lk * 16) ^ sw)];
            a[m_][1] = *(const bf16x8*)&lds[rb + ((64 + lk * 16) ^ sw)];
        }
        #pragma unroll
        for (int n_ = 0; n_ < 4; ++n_) {
            const int rb = 65536 + buf * 16384 + (wc * 64 + n_ * 16 + lm) * 128;
            b[n_][0] = *(const bf16x8*)&lds[rb + ((lk * 16) ^ sw)];
            b[n_][1] = *(const bf16x8*)&lds[rb + ((64 + lk * 16) ^ sw)];
        }
        if (pf) stage(kt + 1);
        asm volatile("s_waitcnt lgkmcnt(0)");
        __builtin_amdgcn_s_setprio(1);
        #pragma unroll
        for (int m_ = 0; m_ < 4; ++m_)
            #pragma unroll
            for (int n_ = 0; n_ < 4; ++n_) {
                acc[m_][n_] = __builtin_amdgcn_mfma_f32_16x16x32_bf16(a[m_][0], b[n_][0], acc[m_][n_], 0, 0, 0);
                acc[m_][n_] = __builtin_amdgcn_mfma_f32_16x16x32_bf16(a[m_][1], b[n_][1], acc[m_][n_], 0, 0, 0);
            }
        __builtin_amdgcn_s_setprio(0);
        if (pf) asm volatile("s_waitcnt vmcnt(0)" ::: "memory");
        __builtin_amdgcn_s_barrier();
    }

    #pragma unroll
    for (int mf = 0; mf < 4; ++mf)
      #pragma unroll
      for (int nf = 0; nf < 4; ++nf)
        #pragma unroll
        for (int r = 0; r < 4; ++r) {
            const int grow = bm * 256 + wr * 64 + mf * 16 + lk * 4 + r;
            const int gcol = bn * 128 + wc * 64 + nf * 16 + lm;
            const long i = (long)grow * N + gcol;
            outp[i] = res[i] + acc[mf][nf][r];
        }
}

// ---------------------------------------------------------------------------
// Windowed causal attention (verified): dbuf staging, 32 q/block.
// ---------------------------------------------------------------------------
__global__ __launch_bounds__(128)
void attn_kernel(const short* __restrict__ Q, const short* __restrict__ Km,
                 int ldq, const short* __restrict__ VT, short* __restrict__ att) {
    const int T = 2048, D = 1024, Mtot = 8192;
    const int bid = blockIdx.x;
    const int b = bid >> 6;
    const int q0 = (bid & 63) << 5;
    const long qrow0 = (long)b * T + q0;
    const int t = threadIdx.x, lane = t & 63, w = t >> 6;

    __shared__ short Qs[2][32 * 32];
    __shared__ short Ks[2][96 * 32];
    __shared__ float S_lds[32][100];
    __shared__ short P_lds[32 * 96];
    __shared__ short VTs[2][128 * 96];

    const int trow = t >> 2, tk8 = (t & 3) * 8;
    auto stageQK = [&](int kt, int bf) {
        const int k0 = kt << 5;
        load_lds16(Q + (qrow0 + trow) * ldq + k0 + tk8, &Qs[bf][t * 8]);
        #pragma unroll
        for (int s2 = 0; s2 < 3; ++s2) {
            const int krow = s2 * 32 + trow;
            int j = q0 - 64 + krow; if (j < 0) j = 0;
            load_lds16(Km + ((long)b * T + j) * ldq + k0 + tk8, &Ks[bf][(s2 * 128 + t) * 8]);
        }
    };

    f32x4 s[6] = {};
    stageQK(0, 0);
    __syncthreads();
    for (int kt = 0; kt < 32; ++kt) {
        const int cb = kt & 1;
        if (kt + 1 < 32) stageQK(kt + 1, cb ^ 1);
        const int ko = (lane >> 4) * 8;
        const bf16x8 aq = *(const bf16x8*)&Qs[cb][(w * 16 + (lane & 15)) * 32 + ko];
        #pragma unroll
        for (int n = 0; n < 6; ++n) {
            const bf16x8 bk = *(const bf16x8*)&Ks[cb][(n * 16 + (lane & 15)) * 32 + ko];
            s[n] = __builtin_amdgcn_mfma_f32_16x16x32_bf16(aq, bk, s[n], 0, 0, 0);
        }
        __syncthreads();
    }
    #pragma unroll
    for (int n = 0; n < 6; ++n)
        #pragma unroll
        for (int r = 0; r < 4; ++r)
            S_lds[w * 16 + ((lane >> 4) << 2) + r][n * 16 + (lane & 15)] = s[n][r] * 0.03125f;
    __syncthreads();

    {
        const int row = t >> 2, c0 = (t & 3) * 24;
        float e[24];
        float mx = -1e30f;
        #pragma unroll
        for (int c = 0; c < 24; ++c) {
            const int kj = c0 + c;
            const bool valid = (kj > row) && (kj <= row + 64) && (q0 - 64 + kj >= 0);
            const float sv = valid ? S_lds[row][kj] : -1e30f;
            e[c] = sv;
            mx = fmaxf(mx, sv);
        }
        mx = fmaxf(mx, __shfl_xor(mx, 1));
        mx = fmaxf(mx, __shfl_xor(mx, 2));
        float sum = 0.f;
        #pragma unroll
        for (int c = 0; c < 24; ++c) {
            const float ev = (e[c] > -1e29f) ? __expf(e[c] - mx) : 0.f;
            e[c] = ev; sum += ev;
        }
        sum += __shfl_xor(sum, 1);
        sum += __shfl_xor(sum, 2);
        const float inv = 1.f / sum;
        #pragma unroll
        for (int c = 0; c < 24; ++c)
            P_lds[row * 96 + c0 + c] = to_bf16s(e[c] * inv);
    }

    auto stageV = [&](int dc, int bf) {
        #pragma unroll
        for (int s2 = 0; s2 < 12; ++s2) {
            const int idx = s2 * 128 + t;
            const int dr = idx / 12, c = idx - dr * 12;
            int j = q0 - 64 + c * 8; if (j < 0) j = 0;
            load_lds16(VT + (long)(dc * 128 + dr) * Mtot + b * T + j, &VTs[bf][idx * 8]);
        }
    };
    stageV(0, 0);
    __syncthreads();

    bf16x8 pa[3];
    {
        const int ko = (lane >> 4) * 8;
        #pragma unroll
        for (int kc = 0; kc < 3; ++kc)
            pa[kc] = *(const bf16x8*)&P_lds[(w * 16 + (lane & 15)) * 96 + kc * 32 + ko];
    }
    for (int dc = 0; dc < 8; ++dc) {
        const int cb = dc & 1;
        if (dc + 1 < 8) stageV(dc + 1, cb ^ 1);
        f32x4 o[8] = {};
        const int ko = (lane >> 4) * 8;
        #pragma unroll
        for (int kc = 0; kc < 3; ++kc)
            #pragma unroll
            for (int n = 0; n < 8; ++n) {
                const bf16x8 vb = *(const bf16x8*)&VTs[cb][(n * 16 + (lane & 15)) * 96 + kc * 32 + ko];
                o[n] = __builtin_amdgcn_mfma_f32_16x16x32_bf16(pa[kc], vb, o[n], 0, 0, 0);
            }
        __syncthreads();
        #pragma unroll
        for (int n = 0; n < 8; ++n)
            #pragma unroll
            for (int r = 0; r < 4; ++r) {
                const long grow = qrow0 + w * 16 + ((lane >> 4) << 2) + r;
                const int gcol = dc * 128 + n * 16 + (lane & 15);
                att[grow * D + gcol] = to_bf16s(o[n][r]);
            }
    }
}

// ---------------------------------------------------------------------------
extern "C" void kernel_launch(void* const* d_in, const int* in_sizes, int n_in,
                              void* d_out, int out_size, void* d_ws, size_t ws_size,
                              hipStream_t stream) {
    const float* x   = (const float*)d_in[0];
    const float* n1w = (const float*)d_in[1];
    const float* n2w = (const float*)d_in[2];
    const float* Wq  = (const float*)d_in[3];
    const float* Wk  = (const float*)d_in[4];
    const float* Wv  = (const float*)d_in[5];
    const float* Wo  = (const float*)d_in[6];
    const float* W1  = (const float*)d_in[7];
    const float* W2  = (const float*)d_in[8];
    const float* W3  = (const float*)d_in[9];

    const int M = 8192;           // B*T
    char* ws = (char*)d_ws;
    size_t off = 0;
    auto alloc = [&](size_t bytes) { void* p = ws + off; off += (bytes + 255) & ~(size_t)255; return p; };

    short* xn1 = (short*)alloc((size_t)M * 1024 * 2);   // reused as att
    short* qk  = (short*)alloc((size_t)M * 2048 * 2);   // q | k rows (ld=2048); xn2/h alias
    short* vT  = (short*)alloc((size_t)M * 1024 * 2);   // V^T [1024][8192]
    float* x2  = (float*)alloc((size_t)M * 1024 * 4);
    short* WqT = (short*)alloc((size_t)1024 * 1024 * 2);   // WqT,WkT,WvT contiguous
    short* WkT = (short*)alloc((size_t)1024 * 1024 * 2);
    short* WvT = (short*)alloc((size_t)1024 * 1024 * 2);
    short* WoT = (short*)alloc((size_t)1024 * 1024 * 2);
    short* W13T= (short*)alloc((size_t)4096 * 1024 * 2);   // interleaved W1/W3
    short* W2T = (short*)alloc((size_t)1024 * 2048 * 2);
    short* att = xn1;                                   // xn1 dead after QKV
    short* xn2 = qk;                                    // q/k dead after attention
    short* h   = qk + (size_t)M * 1024;                 // spans qk 2nd half + vT (32MB)

    // transposes + rmsnorm1 in one launch
    prep_kernel<<<18432, 256, 0, stream>>>(Wq, Wk, Wv, Wo, W1, W3, W2,
                                           WqT, WkT, WvT, WoT, W13T, W2T,
                                           x, n1w, xn1);
    // fused QKV: [M,3072]; gcol<2048 -> qk (ld 2048), else -> vT transposed
    gemm192qkv<<<512, 512, 0, stream>>>(xn1, WqT, qk, vT, M, 3072, 1024);
    // attention -> att (bf16)
    attn_kernel<<<256, 128, 0, stream>>>(qk, qk + 1024, 2048, vT, att);
    // x2 = x + att @ Wo   (fp32)
    gemm128res<<<256, 512, 0, stream>>>(att, WoT, x, x2, M, 1024, 1024);
    // norm2 -> xn2 (bf16)
    rmsnorm_kernel<<<M, 256, 0, stream>>>(x2, n2w, xn2);
    // h = silu(xn2@W1) * (xn2@W3)  — fused interleaved GEMM, N=4096
    gemm256fv2<<<512, 512, 0, stream>>>(xn2, W13T, h, M, 4096, 1024);
    // out = x2 + h @ W2   (fp32)
    gemm128res<<<256, 512, 0, stream>>>(h, W2T, x2, (float*)d_out, M, 1024, 2048);
}

// Round 9
// 301.938 us; speedup vs baseline: 1.0279x; 1.0279x over previous
//
#include <hip/hip_runtime.h>
#include <hip/hip_bf16.h>

typedef __attribute__((ext_vector_type(8))) short bf16x8;
typedef __attribute__((ext_vector_type(4))) float f32x4;

__device__ __forceinline__ short to_bf16s(float f) {
    union { __hip_bfloat16 h; short s; } u;
    u.h = __float2bfloat16(f);
    return u.s;
}

__device__ __forceinline__ void load_lds16(const void* g, void* l) {
    __builtin_amdgcn_global_load_lds((const __attribute__((address_space(1))) void*)g,
                                     (__attribute__((address_space(3))) void*)l, 16, 0, 0);
}

// ---------------------------------------------------------------------------
// prep: blocks [0,10240): weight transposes (fp32 [K][N] -> bf16 [N][K]),
// W1/W3 column-interleaved into W13T[4096][1024].  Blocks [10240,18432):
// rmsnorm1 row (bid-10240) -> xn1 bf16.
// ---------------------------------------------------------------------------
__global__ __launch_bounds__(256)
void prep_kernel(const float* __restrict__ Wq, const float* __restrict__ Wk,
                 const float* __restrict__ Wv, const float* __restrict__ Wo,
                 const float* __restrict__ W1, const float* __restrict__ W3,
                 const float* __restrict__ W2,
                 short* __restrict__ WqT, short* __restrict__ WkT,
                 short* __restrict__ WvT, short* __restrict__ WoT,
                 short* __restrict__ W13T, short* __restrict__ W2T,
                 const float* __restrict__ x, const float* __restrict__ n1w,
                 short* __restrict__ xn1) {
    const int bid = blockIdx.x;
    const int t = threadIdx.x;
    if (bid >= 10240) {
        const long row = bid - 10240;
        float4 v = ((const float4*)(x + row * 1024))[t];
        float ss = v.x * v.x + v.y * v.y + v.z * v.z + v.w * v.w;
        #pragma unroll
        for (int off = 32; off; off >>= 1) ss += __shfl_xor(ss, off);
        __shared__ float red[4];
        if ((t & 63) == 0) red[t >> 6] = ss;
        __syncthreads();
        ss = red[0] + red[1] + red[2] + red[3];
        const float inv = rsqrtf(ss * (1.0f / 1024.0f) + 1e-6f);
        float4 wv = ((const float4*)n1w)[t];
        short4 o;
        o.x = to_bf16s(v.x * inv * wv.x);
        o.y = to_bf16s(v.y * inv * wv.y);
        o.z = to_bf16s(v.z * inv * wv.z);
        o.w = to_bf16s(v.w * inv * wv.w);
        *(short4*)&xn1[row * 1024 + t * 4] = o;
        return;
    }
    __shared__ float tile[32][33];
    const float* src; short* dst; int K, N, tl, rs = 1, ro = 0;
    if (bid < 4096) {
        const int wi = bid >> 10; tl = bid & 1023;
        src = wi == 0 ? Wq : wi == 1 ? Wk : wi == 2 ? Wv : Wo;
        dst = wi == 0 ? WqT : wi == 1 ? WkT : wi == 2 ? WvT : WoT;
        K = 1024; N = 1024;
    } else if (bid < 8192) {
        const int wi = (bid - 4096) >> 11; tl = (bid - 4096) & 2047;
        src = wi ? W3 : W1; dst = W13T; rs = 2; ro = wi;
        K = 1024; N = 2048;
    } else {
        tl = bid - 8192; src = W2; dst = W2T;
        K = 2048; N = 1024;
    }
    const int nx = N >> 5;
    const int n0 = (tl % nx) * 32, k0 = (tl / nx) * 32;
    {
        const int lr = t >> 3, lc = (t & 7) * 4;
        float4 v = *(const float4*)&src[(long)(k0 + lr) * N + n0 + lc];
        tile[lr][lc] = v.x; tile[lr][lc + 1] = v.y;
        tile[lr][lc + 2] = v.z; tile[lr][lc + 3] = v.w;
    }
    __syncthreads();
    {
        const int nr = t >> 3, kc = (t & 7) * 4;
        short4 o;
        o.x = to_bf16s(tile[kc][nr]);
        o.y = to_bf16s(tile[kc + 1][nr]);
        o.z = to_bf16s(tile[kc + 2][nr]);
        o.w = to_bf16s(tile[kc + 3][nr]);
        *(short4*)&dst[(long)((n0 + nr) * rs + ro) * K + k0 + kc] = o;
    }
}

// ---------------------------------------------------------------------------
// RMSNorm (fp32 in) -> bf16 out.  One block per row, D=1024.  (norm2)
// ---------------------------------------------------------------------------
__global__ __launch_bounds__(256)
void rmsnorm_kernel(const float* __restrict__ x, const float* __restrict__ wt,
                    short* __restrict__ out) {
    const long row = blockIdx.x;
    const int t = threadIdx.x;
    float4 v = ((const float4*)(x + row * 1024))[t];
    float ss = v.x * v.x + v.y * v.y + v.z * v.z + v.w * v.w;
    #pragma unroll
    for (int off = 32; off; off >>= 1) ss += __shfl_xor(ss, off);
    __shared__ float red[4];
    if ((t & 63) == 0) red[t >> 6] = ss;
    __syncthreads();
    ss = red[0] + red[1] + red[2] + red[3];
    const float inv = rsqrtf(ss * (1.0f / 1024.0f) + 1e-6f);
    float4 wv = ((const float4*)wt)[t];
    short4 o;
    o.x = to_bf16s(v.x * inv * wv.x);
    o.y = to_bf16s(v.y * inv * wv.y);
    o.z = to_bf16s(v.z * inv * wv.z);
    o.w = to_bf16s(v.w * inv * wv.w);
    *(short4*)&out[row * 1024 + t * 4] = o;
}

// ---------------------------------------------------------------------------
// MFMA phase macro (barrier ; lgkm ; setprio ; 16 MFMA ; barrier).
// ---------------------------------------------------------------------------
#define MFMA16(MB, NB, BREG)                                                   \
    __builtin_amdgcn_s_barrier();                                              \
    asm volatile("s_waitcnt lgkmcnt(0)");                                      \
    __builtin_amdgcn_s_setprio(1);                                             \
    _Pragma("unroll")                                                          \
    for (int m_ = 0; m_ < 4; ++m_)                                             \
        _Pragma("unroll")                                                      \
        for (int n_ = 0; n_ < 2; ++n_) {                                       \
            acc[(MB) + m_][(NB) + n_] = __builtin_amdgcn_mfma_f32_16x16x32_bf16( \
                a[m_][0], BREG[n_][0], acc[(MB) + m_][(NB) + n_], 0, 0, 0);    \
            acc[(MB) + m_][(NB) + n_] = __builtin_amdgcn_mfma_f32_16x16x32_bf16( \
                a[m_][1], BREG[n_][1], acc[(MB) + m_][(NB) + n_], 0, 0, 0);    \
        }                                                                      \
    __builtin_amdgcn_s_setprio(0);                                             \
    __builtin_amdgcn_s_barrier();

// ---------------------------------------------------------------------------
// gemm256T: 256x256 tile, BK=64, 8 waves (2x4) of 128x64, 2-buf dbuf (128K),
// m201-style 8-phase schedule, vmcnt(4) checkpoints (round-7 verified @758TF).
// EPI 5: QKV split — gcol<2048 -> bf16 outp[row][2048] (ld 2048),
//        gcol>=2048 -> transposed bf16 outp2[gcol-2048][8192].
// EPI 6: fused SwiGLU over column-interleaved B (even gcol = W1 col, odd =
//        W3 col): outp[row][gcol/2] = silu(C_even) * C_odd.
// ---------------------------------------------------------------------------
#define RA2(BUF, MG)                                                           \
    _Pragma("unroll")                                                          \
    for (int m_ = 0; m_ < 4; ++m_) {                                           \
        const int rb_ = ((BUF) * 2 + wr) * 16384 + (((MG) * 4 + m_) * 16 + lm) * 128; \
        a[m_][0] = *(const bf16x8*)&lds[rb_ + ((lk * 16) ^ sw)];               \
        a[m_][1] = *(const bf16x8*)&lds[rb_ + ((64 + lk * 16) ^ sw)];          \
    }
#define RB2(BUF, NH, ARR)                                                      \
    _Pragma("unroll")                                                          \
    for (int n_ = 0; n_ < 2; ++n_) {                                           \
        const int rb_ = 65536 + ((BUF) * 2 + (wc >> 1)) * 16384 +              \
                        ((wc & 1) * 64 + ((NH) * 2 + n_) * 16 + lm) * 128;     \
        ARR[n_][0] = *(const bf16x8*)&lds[rb_ + ((lk * 16) ^ sw)];             \
        ARR[n_][1] = *(const bf16x8*)&lds[rb_ + ((64 + lk * 16) ^ sw)];        \
    }

template<int EPI>
__global__ __launch_bounds__(512, 2)
void gemm256T(const short* __restrict__ A, const short* __restrict__ B0,
              short* __restrict__ outp, short* __restrict__ outp2,
              int M, int N, int K) {
    __shared__ __align__(16) char lds[131072];

    const int t = threadIdx.x;
    const int lane = t & 63, w = t >> 6;
    const int wr = w >> 2, wc = w & 3;
    const int lm = lane & 15, lk = lane >> 4;
    const int sw = (lm & 7) << 4;

    const int nbn = N >> 8;
    const int chunk = gridDim.x >> 3;
    const int logical = (blockIdx.x & 7) * chunk + (blockIdx.x >> 3);
    const int bm = logical / nbn, bn = logical - (logical / nbn) * nbn;

    const long Kb = (long)K * 2;
    const char* Ab = (const char*)A;
    const char* Bb = (const char*)B0;

    long srcA[2][2], srcB[2][2];
    {
        const int rowp = t >> 3;
        const int cbx = (t & 7) * 16;
        const int swz = ((t >> 3) & 7) << 4;
        #pragma unroll
        for (int h = 0; h < 2; ++h)
            #pragma unroll
            for (int c = 0; c < 2; ++c) {
                srcA[h][c] = (long)(bm * 256 + h * 128 + c * 64 + rowp) * Kb + (cbx ^ swz);
                srcB[h][c] = (long)(bn * 256 + h * 128 + c * 64 + rowp) * Kb + (cbx ^ swz);
            }
    }
    auto stA = [&](int kt, int h) {
        const int buf = kt & 1;
        #pragma unroll
        for (int c = 0; c < 2; ++c)
            load_lds16(Ab + srcA[h][c] + (long)kt * 128,
                       &lds[(buf * 2 + h) * 16384 + c * 8192 + t * 16]);
    };
    auto stB = [&](int kt, int h) {
        const int buf = kt & 1;
        #pragma unroll
        for (int c = 0; c < 2; ++c)
            load_lds16(Bb + srcB[h][c] + (long)kt * 128,
                       &lds[65536 + (buf * 2 + h) * 16384 + c * 8192 + t * 16]);
    };

    f32x4 acc[8][4] = {};
    bf16x8 a[4][2], b0[2][2], b1[2][2];
    const int nt = K >> 6;

    stB(0, 0); stB(0, 1); stA(0, 0); stA(0, 1); stB(1, 0); stB(1, 1);
    asm volatile("s_waitcnt vmcnt(4)" ::: "memory");
    __builtin_amdgcn_s_barrier();

    for (int u = 0; u < nt; u += 2) {
        const bool pf = (u + 2) < nt;
        RA2(0, 0); RB2(0, 0, b0);
        stA(u + 1, 0);
        MFMA16(0, 0, b0)
        RB2(0, 1, b1);
        stA(u + 1, 1);
        MFMA16(0, 2, b1)
        RA2(0, 1);
        if (pf) stB(u + 2, 0);
        MFMA16(4, 2, b1)
        if (pf) { stB(u + 2, 1); asm volatile("s_waitcnt vmcnt(4)" ::: "memory"); }
        else    { asm volatile("s_waitcnt vmcnt(0)" ::: "memory"); }
        MFMA16(4, 0, b0)
        RA2(1, 0); RB2(1, 0, b0);
        if (pf) stA(u + 2, 0);
        MFMA16(0, 0, b0)
        RB2(1, 1, b1);
        if (pf) stA(u + 2, 1);
        MFMA16(0, 2, b1)
        RA2(1, 1);
        if (pf) stB(u + 3, 0);
        MFMA16(4, 2, b1)
        if (pf) { stB(u + 3, 1); asm volatile("s_waitcnt vmcnt(4)" ::: "memory"); }
        else    { asm volatile("s_waitcnt vmcnt(0)" ::: "memory"); }
        MFMA16(4, 0, b0)
    }

    const int NH = N >> 1;
    #pragma unroll
    for (int mf = 0; mf < 8; ++mf)
      #pragma unroll
      for (int nf = 0; nf < 4; ++nf)
        #pragma unroll
        for (int r = 0; r < 4; ++r) {
            const int grow = bm * 256 + wr * 128 + mf * 16 + lk * 4 + r;
            const int gcol = bn * 256 + wc * 64 + nf * 16 + lm;
            const float v = acc[mf][nf][r];
            if constexpr (EPI == 5) {
                if (gcol < 2048)
                    outp[(long)grow * 2048 + gcol] = to_bf16s(v);
                else
                    outp2[(long)(gcol - 2048) * 8192 + grow] = to_bf16s(v);
            } else {   // EPI 6: SwiGLU pair via lane-xor
                const float g3 = __shfl_xor(v, 1);
                if (!(lane & 1)) {
                    const float sws = v / (1.f + __expf(-v));
                    outp[(long)grow * NH + (gcol >> 1)] = to_bf16s(sws * g3);
                }
            }
        }
}

// ---------------------------------------------------------------------------
// gemm128o: 128x128 tile, BK=64, 256 threads (4 waves 2x2, wave 64x64),
// 64 KiB LDS dbuf -> 2 blocks/CU.  Plain stage->read->MFMA->syncthreads loop,
// swizzled LDS, XCD chunking.  out = res + C (fp32).  (round-7 verified)
// ---------------------------------------------------------------------------
__global__ __launch_bounds__(256, 2)
void gemm128o(const short* __restrict__ A, const short* __restrict__ B0,
              const float* __restrict__ res, float* __restrict__ outp,
              int M, int N, int K) {
    __shared__ __align__(16) char lds[65536];   // A: 2x16K @0, B: 2x16K @32768

    const int t = threadIdx.x;
    const int lane = t & 63, w = t >> 6;
    const int wr = w >> 1, wc = w & 1;
    const int lm = lane & 15, lk = lane >> 4;
    const int sw = (lm & 7) << 4;

    const int nbn = N >> 7;
    const int chunk = gridDim.x >> 3;
    const int logical = (blockIdx.x & 7) * chunk + (blockIdx.x >> 3);
    const int bm = logical / nbn, bn = logical - (logical / nbn) * nbn;

    const long Kb = (long)K * 2;
    const char* Ab = (const char*)A;
    const char* Bb = (const char*)B0;

    long srcA[4], srcB[4];
    {
        const int rowp = t >> 3;                 // + c*32
        const int cbx = (t & 7) * 16;
        const int swz = ((t >> 3) & 7) << 4;
        #pragma unroll
        for (int c = 0; c < 4; ++c) {
            srcA[c] = (long)(bm * 128 + c * 32 + rowp) * Kb + (cbx ^ swz);
            srcB[c] = (long)(bn * 128 + c * 32 + rowp) * Kb + (cbx ^ swz);
        }
    }
    auto stage = [&](int kt, int buf) {
        #pragma unroll
        for (int c = 0; c < 4; ++c)
            load_lds16(Ab + srcA[c] + (long)kt * 128,
                       &lds[buf * 16384 + c * 4096 + t * 16]);
        #pragma unroll
        for (int c = 0; c < 4; ++c)
            load_lds16(Bb + srcB[c] + (long)kt * 128,
                       &lds[32768 + buf * 16384 + c * 4096 + t * 16]);
    };

    f32x4 acc[4][4] = {};
    const int nt = K >> 6;

    stage(0, 0);
    asm volatile("s_waitcnt vmcnt(0)" ::: "memory");
    __syncthreads();

    for (int kt = 0; kt < nt; ++kt) {
        const int buf = kt & 1;
        if (kt + 1 < nt) stage(kt + 1, buf ^ 1);
        bf16x8 a[4][2], b[4][2];
        #pragma unroll
        for (int m = 0; m < 4; ++m) {
            const int rb = buf * 16384 + (wr * 64 + m * 16 + lm) * 128;
            a[m][0] = *(const bf16x8*)&lds[rb + ((lk * 16) ^ sw)];
            a[m][1] = *(const bf16x8*)&lds[rb + ((64 + lk * 16) ^ sw)];
        }
        #pragma unroll
        for (int n = 0; n < 4; ++n) {
            const int rb = 32768 + buf * 16384 + (wc * 64 + n * 16 + lm) * 128;
            b[n][0] = *(const bf16x8*)&lds[rb + ((lk * 16) ^ sw)];
            b[n][1] = *(const bf16x8*)&lds[rb + ((64 + lk * 16) ^ sw)];
        }
        #pragma unroll
        for (int m = 0; m < 4; ++m)
            #pragma unroll
            for (int n = 0; n < 4; ++n) {
                acc[m][n] = __builtin_amdgcn_mfma_f32_16x16x32_bf16(a[m][0], b[n][0], acc[m][n], 0, 0, 0);
                acc[m][n] = __builtin_amdgcn_mfma_f32_16x16x32_bf16(a[m][1], b[n][1], acc[m][n], 0, 0, 0);
            }
        __syncthreads();
    }

    #pragma unroll
    for (int m = 0; m < 4; ++m)
      #pragma unroll
      for (int n = 0; n < 4; ++n)
        #pragma unroll
        for (int r = 0; r < 4; ++r) {
            const int grow = bm * 128 + wr * 64 + m * 16 + lk * 4 + r;
            const int gcol = bn * 128 + wc * 64 + n * 16 + lm;
            const long i = (long)grow * N + gcol;
            outp[i] = res[i] + acc[m][n][r];
        }
}

// ---------------------------------------------------------------------------
// Windowed causal attention (verified): dbuf staging, 32 q/block.
// ---------------------------------------------------------------------------
__global__ __launch_bounds__(128)
void attn_kernel(const short* __restrict__ Q, const short* __restrict__ Km,
                 int ldq, const short* __restrict__ VT, short* __restrict__ att) {
    const int T = 2048, D = 1024, Mtot = 8192;
    const int bid = blockIdx.x;
    const int b = bid >> 6;
    const int q0 = (bid & 63) << 5;
    const long qrow0 = (long)b * T + q0;
    const int t = threadIdx.x, lane = t & 63, w = t >> 6;

    __shared__ short Qs[2][32 * 32];
    __shared__ short Ks[2][96 * 32];
    __shared__ float S_lds[32][100];
    __shared__ short P_lds[32 * 96];
    __shared__ short VTs[2][128 * 96];

    const int trow = t >> 2, tk8 = (t & 3) * 8;
    auto stageQK = [&](int kt, int bf) {
        const int k0 = kt << 5;
        load_lds16(Q + (qrow0 + trow) * ldq + k0 + tk8, &Qs[bf][t * 8]);
        #pragma unroll
        for (int s2 = 0; s2 < 3; ++s2) {
            const int krow = s2 * 32 + trow;
            int j = q0 - 64 + krow; if (j < 0) j = 0;
            load_lds16(Km + ((long)b * T + j) * ldq + k0 + tk8, &Ks[bf][(s2 * 128 + t) * 8]);
        }
    };

    f32x4 s[6] = {};
    stageQK(0, 0);
    __syncthreads();
    for (int kt = 0; kt < 32; ++kt) {
        const int cb = kt & 1;
        if (kt + 1 < 32) stageQK(kt + 1, cb ^ 1);
        const int ko = (lane >> 4) * 8;
        const bf16x8 aq = *(const bf16x8*)&Qs[cb][(w * 16 + (lane & 15)) * 32 + ko];
        #pragma unroll
        for (int n = 0; n < 6; ++n) {
            const bf16x8 bk = *(const bf16x8*)&Ks[cb][(n * 16 + (lane & 15)) * 32 + ko];
            s[n] = __builtin_amdgcn_mfma_f32_16x16x32_bf16(aq, bk, s[n], 0, 0, 0);
        }
        __syncthreads();
    }
    #pragma unroll
    for (int n = 0; n < 6; ++n)
        #pragma unroll
        for (int r = 0; r < 4; ++r)
            S_lds[w * 16 + ((lane >> 4) << 2) + r][n * 16 + (lane & 15)] = s[n][r] * 0.03125f;
    __syncthreads();

    {
        const int row = t >> 2, c0 = (t & 3) * 24;
        float e[24];
        float mx = -1e30f;
        #pragma unroll
        for (int c = 0; c < 24; ++c) {
            const int kj = c0 + c;
            const bool valid = (kj > row) && (kj <= row + 64) && (q0 - 64 + kj >= 0);
            const float sv = valid ? S_lds[row][kj] : -1e30f;
            e[c] = sv;
            mx = fmaxf(mx, sv);
        }
        mx = fmaxf(mx, __shfl_xor(mx, 1));
        mx = fmaxf(mx, __shfl_xor(mx, 2));
        float sum = 0.f;
        #pragma unroll
        for (int c = 0; c < 24; ++c) {
            const float ev = (e[c] > -1e29f) ? __expf(e[c] - mx) : 0.f;
            e[c] = ev; sum += ev;
        }
        sum += __shfl_xor(sum, 1);
        sum += __shfl_xor(sum, 2);
        const float inv = 1.f / sum;
        #pragma unroll
        for (int c = 0; c < 24; ++c)
            P_lds[row * 96 + c0 + c] = to_bf16s(e[c] * inv);
    }

    auto stageV = [&](int dc, int bf) {
        #pragma unroll
        for (int s2 = 0; s2 < 12; ++s2) {
            const int idx = s2 * 128 + t;
            const int dr = idx / 12, c = idx - dr * 12;
            int j = q0 - 64 + c * 8; if (j < 0) j = 0;
            load_lds16(VT + (long)(dc * 128 + dr) * Mtot + b * T + j, &VTs[bf][idx * 8]);
        }
    };
    stageV(0, 0);
    __syncthreads();

    bf16x8 pa[3];
    {
        const int ko = (lane >> 4) * 8;
        #pragma unroll
        for (int kc = 0; kc < 3; ++kc)
            pa[kc] = *(const bf16x8*)&P_lds[(w * 16 + (lane & 15)) * 96 + kc * 32 + ko];
    }
    for (int dc = 0; dc < 8; ++dc) {
        const int cb = dc & 1;
        if (dc + 1 < 8) stageV(dc + 1, cb ^ 1);
        f32x4 o[8] = {};
        const int ko = (lane >> 4) * 8;
        #pragma unroll
        for (int kc = 0; kc < 3; ++kc)
            #pragma unroll
            for (int n = 0; n < 8; ++n) {
                const bf16x8 vb = *(const bf16x8*)&VTs[cb][(n * 16 + (lane & 15)) * 96 + kc * 32 + ko];
                o[n] = __builtin_amdgcn_mfma_f32_16x16x32_bf16(pa[kc], vb, o[n], 0, 0, 0);
            }
        __syncthreads();
        #pragma unroll
        for (int n = 0; n < 8; ++n)
            #pragma unroll
            for (int r = 0; r < 4; ++r) {
                const long grow = qrow0 + w * 16 + ((lane >> 4) << 2) + r;
                const int gcol = dc * 128 + n * 16 + (lane & 15);
                att[grow * D + gcol] = to_bf16s(o[n][r]);
            }
    }
}

// ---------------------------------------------------------------------------
extern "C" void kernel_launch(void* const* d_in, const int* in_sizes, int n_in,
                              void* d_out, int out_size, void* d_ws, size_t ws_size,
                              hipStream_t stream) {
    const float* x   = (const float*)d_in[0];
    const float* n1w = (const float*)d_in[1];
    const float* n2w = (const float*)d_in[2];
    const float* Wq  = (const float*)d_in[3];
    const float* Wk  = (const float*)d_in[4];
    const float* Wv  = (const float*)d_in[5];
    const float* Wo  = (const float*)d_in[6];
    const float* W1  = (const float*)d_in[7];
    const float* W2  = (const float*)d_in[8];
    const float* W3  = (const float*)d_in[9];

    const int M = 8192;           // B*T
    char* ws = (char*)d_ws;
    size_t off = 0;
    auto alloc = [&](size_t bytes) { void* p = ws + off; off += (bytes + 255) & ~(size_t)255; return p; };

    short* xn1 = (short*)alloc((size_t)M * 1024 * 2);   // reused as att
    short* qk  = (short*)alloc((size_t)M * 2048 * 2);   // q | k rows (ld=2048); xn2/h alias
    short* vT  = (short*)alloc((size_t)M * 1024 * 2);   // V^T [1024][8192]
    float* x2  = (float*)alloc((size_t)M * 1024 * 4);
    short* WqT = (short*)alloc((size_t)1024 * 1024 * 2);   // WqT,WkT,WvT contiguous
    short* WkT = (short*)alloc((size_t)1024 * 1024 * 2);
    short* WvT = (short*)alloc((size_t)1024 * 1024 * 2);
    short* WoT = (short*)alloc((size_t)1024 * 1024 * 2);
    short* W13T= (short*)alloc((size_t)4096 * 1024 * 2);   // interleaved W1/W3
    short* W2T = (short*)alloc((size_t)1024 * 2048 * 2);
    short* att = xn1;                                   // xn1 dead after QKV
    short* xn2 = qk;                                    // q/k dead after attention
    short* h   = qk + (size_t)M * 1024;                 // spans qk 2nd half + vT (32MB)

    // transposes + rmsnorm1 in one launch
    prep_kernel<<<18432, 256, 0, stream>>>(Wq, Wk, Wv, Wo, W1, W3, W2,
                                           WqT, WkT, WvT, WoT, W13T, W2T,
                                           x, n1w, xn1);
    // fused QKV on the 8-phase 256^2 structure: [M,3072], grid 384
    gemm256T<5><<<384, 512, 0, stream>>>(xn1, WqT, qk, vT, M, 3072, 1024);
    // attention -> att (bf16)
    attn_kernel<<<256, 128, 0, stream>>>(qk, qk + 1024, 2048, vT, att);
    // x2 = x + att @ Wo   (fp32)
    gemm128o<<<512, 256, 0, stream>>>(att, WoT, x, x2, M, 1024, 1024);
    // norm2 -> xn2 (bf16)
    rmsnorm_kernel<<<M, 256, 0, stream>>>(x2, n2w, xn2);
    // h = silu(xn2@W1) * (xn2@W3)  — fused interleaved GEMM, N=4096
    gemm256T<6><<<512, 512, 0, stream>>>(xn2, W13T, h, nullptr, M, 4096, 1024);
    // out = x2 + h @ W2   (fp32)
    gemm128o<<<512, 256, 0, stream>>>(h, W2T, x2, (float*)d_out, M, 1024, 2048);
}

// Round 10
// 301.427 us; speedup vs baseline: 1.0297x; 1.0017x over previous
//
#include <hip/hip_runtime.h>
#include <hip/hip_bf16.h>

typedef __attribute__((ext_vector_type(8))) short bf16x8;
typedef __attribute__((ext_vector_type(4))) float f32x4;

__device__ __forceinline__ short to_bf16s(float f) {
    union { __hip_bfloat16 h; short s; } u;
    u.h = __float2bfloat16(f);
    return u.s;
}

__device__ __forceinline__ void load_lds16(const void* g, void* l) {
    __builtin_amdgcn_global_load_lds((const __attribute__((address_space(1))) void*)g,
                                     (__attribute__((address_space(3))) void*)l, 16, 0, 0);
}

// ---------------------------------------------------------------------------
// prep: blocks [0,10240): weight transposes (fp32 [K][N] -> bf16 [N][K]),
// W1/W3 column-interleaved into W13T[4096][1024].  Blocks [10240,18432):
// rmsnorm1 row (bid-10240) -> xn1 bf16.
// ---------------------------------------------------------------------------
__global__ __launch_bounds__(256)
void prep_kernel(const float* __restrict__ Wq, const float* __restrict__ Wk,
                 const float* __restrict__ Wv, const float* __restrict__ Wo,
                 const float* __restrict__ W1, const float* __restrict__ W3,
                 const float* __restrict__ W2,
                 short* __restrict__ WqT, short* __restrict__ WkT,
                 short* __restrict__ WvT, short* __restrict__ WoT,
                 short* __restrict__ W13T, short* __restrict__ W2T,
                 const float* __restrict__ x, const float* __restrict__ n1w,
                 short* __restrict__ xn1) {
    const int bid = blockIdx.x;
    const int t = threadIdx.x;
    if (bid >= 10240) {
        const long row = bid - 10240;
        float4 v = ((const float4*)(x + row * 1024))[t];
        float ss = v.x * v.x + v.y * v.y + v.z * v.z + v.w * v.w;
        #pragma unroll
        for (int off = 32; off; off >>= 1) ss += __shfl_xor(ss, off);
        __shared__ float red[4];
        if ((t & 63) == 0) red[t >> 6] = ss;
        __syncthreads();
        ss = red[0] + red[1] + red[2] + red[3];
        const float inv = rsqrtf(ss * (1.0f / 1024.0f) + 1e-6f);
        float4 wv = ((const float4*)n1w)[t];
        short4 o;
        o.x = to_bf16s(v.x * inv * wv.x);
        o.y = to_bf16s(v.y * inv * wv.y);
        o.z = to_bf16s(v.z * inv * wv.z);
        o.w = to_bf16s(v.w * inv * wv.w);
        *(short4*)&xn1[row * 1024 + t * 4] = o;
        return;
    }
    __shared__ float tile[32][33];
    const float* src; short* dst; int K, N, tl, rs = 1, ro = 0;
    if (bid < 4096) {
        const int wi = bid >> 10; tl = bid & 1023;
        src = wi == 0 ? Wq : wi == 1 ? Wk : wi == 2 ? Wv : Wo;
        dst = wi == 0 ? WqT : wi == 1 ? WkT : wi == 2 ? WvT : WoT;
        K = 1024; N = 1024;
    } else if (bid < 8192) {
        const int wi = (bid - 4096) >> 11; tl = (bid - 4096) & 2047;
        src = wi ? W3 : W1; dst = W13T; rs = 2; ro = wi;
        K = 1024; N = 2048;
    } else {
        tl = bid - 8192; src = W2; dst = W2T;
        K = 2048; N = 1024;
    }
    const int nx = N >> 5;
    const int n0 = (tl % nx) * 32, k0 = (tl / nx) * 32;
    {
        const int lr = t >> 3, lc = (t & 7) * 4;
        float4 v = *(const float4*)&src[(long)(k0 + lr) * N + n0 + lc];
        tile[lr][lc] = v.x; tile[lr][lc + 1] = v.y;
        tile[lr][lc + 2] = v.z; tile[lr][lc + 3] = v.w;
    }
    __syncthreads();
    {
        const int nr = t >> 3, kc = (t & 7) * 4;
        short4 o;
        o.x = to_bf16s(tile[kc][nr]);
        o.y = to_bf16s(tile[kc + 1][nr]);
        o.z = to_bf16s(tile[kc + 2][nr]);
        o.w = to_bf16s(tile[kc + 3][nr]);
        *(short4*)&dst[(long)((n0 + nr) * rs + ro) * K + k0 + kc] = o;
    }
}

// ---------------------------------------------------------------------------
// RMSNorm (fp32 in) -> bf16 out.  One block per row, D=1024.  (norm2)
// ---------------------------------------------------------------------------
__global__ __launch_bounds__(256)
void rmsnorm_kernel(const float* __restrict__ x, const float* __restrict__ wt,
                    short* __restrict__ out) {
    const long row = blockIdx.x;
    const int t = threadIdx.x;
    float4 v = ((const float4*)(x + row * 1024))[t];
    float ss = v.x * v.x + v.y * v.y + v.z * v.z + v.w * v.w;
    #pragma unroll
    for (int off = 32; off; off >>= 1) ss += __shfl_xor(ss, off);
    __shared__ float red[4];
    if ((t & 63) == 0) red[t >> 6] = ss;
    __syncthreads();
    ss = red[0] + red[1] + red[2] + red[3];
    const float inv = rsqrtf(ss * (1.0f / 1024.0f) + 1e-6f);
    float4 wv = ((const float4*)wt)[t];
    short4 o;
    o.x = to_bf16s(v.x * inv * wv.x);
    o.y = to_bf16s(v.y * inv * wv.y);
    o.z = to_bf16s(v.z * inv * wv.z);
    o.w = to_bf16s(v.w * inv * wv.w);
    *(short4*)&out[row * 1024 + t * 4] = o;
}

// ---------------------------------------------------------------------------
// MFMA phase macro (barrier ; lgkm ; setprio ; 16 MFMA ; barrier).
// ---------------------------------------------------------------------------
#define MFMA16(MB, NB, BREG)                                                   \
    __builtin_amdgcn_s_barrier();                                              \
    asm volatile("s_waitcnt lgkmcnt(0)");                                      \
    __builtin_amdgcn_s_setprio(1);                                             \
    _Pragma("unroll")                                                          \
    for (int m_ = 0; m_ < 4; ++m_)                                             \
        _Pragma("unroll")                                                      \
        for (int n_ = 0; n_ < 2; ++n_) {                                       \
            acc[(MB) + m_][(NB) + n_] = __builtin_amdgcn_mfma_f32_16x16x32_bf16( \
                a[m_][0], BREG[n_][0], acc[(MB) + m_][(NB) + n_], 0, 0, 0);    \
            acc[(MB) + m_][(NB) + n_] = __builtin_amdgcn_mfma_f32_16x16x32_bf16( \
                a[m_][1], BREG[n_][1], acc[(MB) + m_][(NB) + n_], 0, 0, 0);    \
        }                                                                      \
    __builtin_amdgcn_s_setprio(0);                                             \
    __builtin_amdgcn_s_barrier();

// ---------------------------------------------------------------------------
// gemm256T: 256x256 tile, BK=64, 8 waves (2x4) of 128x64, 2-buf dbuf (128K),
// m201-style 8-phase schedule, vmcnt(4) checkpoints (round-7 verified @758TF).
// EPI 5: QKV split — gcol<2048 -> bf16 outp[row][2048] (ld 2048),
//        gcol>=2048 -> transposed bf16 outp2[gcol-2048][8192].
// EPI 6: fused SwiGLU over column-interleaved B (even gcol = W1 col, odd =
//        W3 col): outp[row][gcol/2] = silu(C_even) * C_odd.
// ---------------------------------------------------------------------------
#define RA2(BUF, MG)                                                           \
    _Pragma("unroll")                                                          \
    for (int m_ = 0; m_ < 4; ++m_) {                                           \
        const int rb_ = ((BUF) * 2 + wr) * 16384 + (((MG) * 4 + m_) * 16 + lm) * 128; \
        a[m_][0] = *(const bf16x8*)&lds[rb_ + ((lk * 16) ^ sw)];               \
        a[m_][1] = *(const bf16x8*)&lds[rb_ + ((64 + lk * 16) ^ sw)];          \
    }
#define RB2(BUF, NH, ARR)                                                      \
    _Pragma("unroll")                                                          \
    for (int n_ = 0; n_ < 2; ++n_) {                                           \
        const int rb_ = 65536 + ((BUF) * 2 + (wc >> 1)) * 16384 +              \
                        ((wc & 1) * 64 + ((NH) * 2 + n_) * 16 + lm) * 128;     \
        ARR[n_][0] = *(const bf16x8*)&lds[rb_ + ((lk * 16) ^ sw)];             \
        ARR[n_][1] = *(const bf16x8*)&lds[rb_ + ((64 + lk * 16) ^ sw)];        \
    }

template<int EPI>
__global__ __launch_bounds__(512, 2)
void gemm256T(const short* __restrict__ A, const short* __restrict__ B0,
              short* __restrict__ outp, short* __restrict__ outp2,
              int M, int N, int K) {
    __shared__ __align__(16) char lds[131072];

    const int t = threadIdx.x;
    const int lane = t & 63, w = t >> 6;
    const int wr = w >> 2, wc = w & 3;
    const int lm = lane & 15, lk = lane >> 4;
    const int sw = (lm & 7) << 4;

    const int nbn = N >> 8;
    const int chunk = gridDim.x >> 3;
    const int logical = (blockIdx.x & 7) * chunk + (blockIdx.x >> 3);
    const int bm = logical / nbn, bn = logical - (logical / nbn) * nbn;

    const long Kb = (long)K * 2;
    const char* Ab = (const char*)A;
    const char* Bb = (const char*)B0;

    long srcA[2][2], srcB[2][2];
    {
        const int rowp = t >> 3;
        const int cbx = (t & 7) * 16;
        const int swz = ((t >> 3) & 7) << 4;
        #pragma unroll
        for (int h = 0; h < 2; ++h)
            #pragma unroll
            for (int c = 0; c < 2; ++c) {
                srcA[h][c] = (long)(bm * 256 + h * 128 + c * 64 + rowp) * Kb + (cbx ^ swz);
                srcB[h][c] = (long)(bn * 256 + h * 128 + c * 64 + rowp) * Kb + (cbx ^ swz);
            }
    }
    auto stA = [&](int kt, int h) {
        const int buf = kt & 1;
        #pragma unroll
        for (int c = 0; c < 2; ++c)
            load_lds16(Ab + srcA[h][c] + (long)kt * 128,
                       &lds[(buf * 2 + h) * 16384 + c * 8192 + t * 16]);
    };
    auto stB = [&](int kt, int h) {
        const int buf = kt & 1;
        #pragma unroll
        for (int c = 0; c < 2; ++c)
            load_lds16(Bb + srcB[h][c] + (long)kt * 128,
                       &lds[65536 + (buf * 2 + h) * 16384 + c * 8192 + t * 16]);
    };

    f32x4 acc[8][4] = {};
    bf16x8 a[4][2], b0[2][2], b1[2][2];
    const int nt = K >> 6;

    stB(0, 0); stB(0, 1); stA(0, 0); stA(0, 1); stB(1, 0); stB(1, 1);
    asm volatile("s_waitcnt vmcnt(4)" ::: "memory");
    __builtin_amdgcn_s_barrier();

    for (int u = 0; u < nt; u += 2) {
        const bool pf = (u + 2) < nt;
        RA2(0, 0); RB2(0, 0, b0);
        stA(u + 1, 0);
        MFMA16(0, 0, b0)
        RB2(0, 1, b1);
        stA(u + 1, 1);
        MFMA16(0, 2, b1)
        RA2(0, 1);
        if (pf) stB(u + 2, 0);
        MFMA16(4, 2, b1)
        if (pf) { stB(u + 2, 1); asm volatile("s_waitcnt vmcnt(4)" ::: "memory"); }
        else    { asm volatile("s_waitcnt vmcnt(0)" ::: "memory"); }
        MFMA16(4, 0, b0)
        RA2(1, 0); RB2(1, 0, b0);
        if (pf) stA(u + 2, 0);
        MFMA16(0, 0, b0)
        RB2(1, 1, b1);
        if (pf) stA(u + 2, 1);
        MFMA16(0, 2, b1)
        RA2(1, 1);
        if (pf) stB(u + 3, 0);
        MFMA16(4, 2, b1)
        if (pf) { stB(u + 3, 1); asm volatile("s_waitcnt vmcnt(4)" ::: "memory"); }
        else    { asm volatile("s_waitcnt vmcnt(0)" ::: "memory"); }
        MFMA16(4, 0, b0)
    }

    const int NH = N >> 1;
    #pragma unroll
    for (int mf = 0; mf < 8; ++mf)
      #pragma unroll
      for (int nf = 0; nf < 4; ++nf)
        #pragma unroll
        for (int r = 0; r < 4; ++r) {
            const int grow = bm * 256 + wr * 128 + mf * 16 + lk * 4 + r;
            const int gcol = bn * 256 + wc * 64 + nf * 16 + lm;
            const float v = acc[mf][nf][r];
            if constexpr (EPI == 5) {
                if (gcol < 2048)
                    outp[(long)grow * 2048 + gcol] = to_bf16s(v);
                else
                    outp2[(long)(gcol - 2048) * 8192 + grow] = to_bf16s(v);
            } else {   // EPI 6: SwiGLU pair via lane-xor
                const float g3 = __shfl_xor(v, 1);
                if (!(lane & 1)) {
                    const float sws = v / (1.f + __expf(-v));
                    outp[(long)grow * NH + (gcol >> 1)] = to_bf16s(sws * g3);
                }
            }
        }
}

// ---------------------------------------------------------------------------
// gemm128o: 128x128 tile, BK=64, 256 threads (4 waves 2x2, wave 64x64),
// 64 KiB LDS dbuf -> 2 blocks/CU.  Plain stage->read->MFMA->syncthreads loop,
// swizzled LDS, XCD chunking.  out = res + C (fp32).  (round-7 verified)
// ---------------------------------------------------------------------------
__global__ __launch_bounds__(256, 2)
void gemm128o(const short* __restrict__ A, const short* __restrict__ B0,
              const float* __restrict__ res, float* __restrict__ outp,
              int M, int N, int K) {
    __shared__ __align__(16) char lds[65536];   // A: 2x16K @0, B: 2x16K @32768

    const int t = threadIdx.x;
    const int lane = t & 63, w = t >> 6;
    const int wr = w >> 1, wc = w & 1;
    const int lm = lane & 15, lk = lane >> 4;
    const int sw = (lm & 7) << 4;

    const int nbn = N >> 7;
    const int chunk = gridDim.x >> 3;
    const int logical = (blockIdx.x & 7) * chunk + (blockIdx.x >> 3);
    const int bm = logical / nbn, bn = logical - (logical / nbn) * nbn;

    const long Kb = (long)K * 2;
    const char* Ab = (const char*)A;
    const char* Bb = (const char*)B0;

    long srcA[4], srcB[4];
    {
        const int rowp = t >> 3;                 // + c*32
        const int cbx = (t & 7) * 16;
        const int swz = ((t >> 3) & 7) << 4;
        #pragma unroll
        for (int c = 0; c < 4; ++c) {
            srcA[c] = (long)(bm * 128 + c * 32 + rowp) * Kb + (cbx ^ swz);
            srcB[c] = (long)(bn * 128 + c * 32 + rowp) * Kb + (cbx ^ swz);
        }
    }
    auto stage = [&](int kt, int buf) {
        #pragma unroll
        for (int c = 0; c < 4; ++c)
            load_lds16(Ab + srcA[c] + (long)kt * 128,
                       &lds[buf * 16384 + c * 4096 + t * 16]);
        #pragma unroll
        for (int c = 0; c < 4; ++c)
            load_lds16(Bb + srcB[c] + (long)kt * 128,
                       &lds[32768 + buf * 16384 + c * 4096 + t * 16]);
    };

    f32x4 acc[4][4] = {};
    const int nt = K >> 6;

    stage(0, 0);
    asm volatile("s_waitcnt vmcnt(0)" ::: "memory");
    __syncthreads();

    for (int kt = 0; kt < nt; ++kt) {
        const int buf = kt & 1;
        if (kt + 1 < nt) stage(kt + 1, buf ^ 1);
        bf16x8 a[4][2], b[4][2];
        #pragma unroll
        for (int m = 0; m < 4; ++m) {
            const int rb = buf * 16384 + (wr * 64 + m * 16 + lm) * 128;
            a[m][0] = *(const bf16x8*)&lds[rb + ((lk * 16) ^ sw)];
            a[m][1] = *(const bf16x8*)&lds[rb + ((64 + lk * 16) ^ sw)];
        }
        #pragma unroll
        for (int n = 0; n < 4; ++n) {
            const int rb = 32768 + buf * 16384 + (wc * 64 + n * 16 + lm) * 128;
            b[n][0] = *(const bf16x8*)&lds[rb + ((lk * 16) ^ sw)];
            b[n][1] = *(const bf16x8*)&lds[rb + ((64 + lk * 16) ^ sw)];
        }
        #pragma unroll
        for (int m = 0; m < 4; ++m)
            #pragma unroll
            for (int n = 0; n < 4; ++n) {
                acc[m][n] = __builtin_amdgcn_mfma_f32_16x16x32_bf16(a[m][0], b[n][0], acc[m][n], 0, 0, 0);
                acc[m][n] = __builtin_amdgcn_mfma_f32_16x16x32_bf16(a[m][1], b[n][1], acc[m][n], 0, 0, 0);
            }
        __syncthreads();
    }

    #pragma unroll
    for (int m = 0; m < 4; ++m)
      #pragma unroll
      for (int n = 0; n < 4; ++n)
        #pragma unroll
        for (int r = 0; r < 4; ++r) {
            const int grow = bm * 128 + wr * 64 + m * 16 + lk * 4 + r;
            const int gcol = bn * 128 + wc * 64 + n * 16 + lm;
            const long i = (long)grow * N + gcol;
            outp[i] = res[i] + acc[m][n][r];
        }
}

// ---------------------------------------------------------------------------
// Windowed causal attention (verified): dbuf staging, 32 q/block.
// ---------------------------------------------------------------------------
__global__ __launch_bounds__(128)
void attn_kernel(const short* __restrict__ Q, const short* __restrict__ Km,
                 int ldq, const short* __restrict__ VT, short* __restrict__ att) {
    const int T = 2048, D = 1024, Mtot = 8192;
    const int bid = blockIdx.x;
    const int b = bid >> 6;
    const int q0 = (bid & 63) << 5;
    const long qrow0 = (long)b * T + q0;
    const int t = threadIdx.x, lane = t & 63, w = t >> 6;

    __shared__ short Qs[2][32 * 32];
    __shared__ short Ks[2][96 * 32];
    __shared__ float S_lds[32][100];
    __shared__ short P_lds[32 * 96];
    __shared__ short VTs[2][128 * 96];

    const int trow = t >> 2, tk8 = (t & 3) * 8;
    auto stageQK = [&](int kt, int bf) {
        const int k0 = kt << 5;
        load_lds16(Q + (qrow0 + trow) * ldq + k0 + tk8, &Qs[bf][t * 8]);
        #pragma unroll
        for (int s2 = 0; s2 < 3; ++s2) {
            const int krow = s2 * 32 + trow;
            int j = q0 - 64 + krow; if (j < 0) j = 0;
            load_lds16(Km + ((long)b * T + j) * ldq + k0 + tk8, &Ks[bf][(s2 * 128 + t) * 8]);
        }
    };

    f32x4 s[6] = {};
    stageQK(0, 0);
    __syncthreads();
    for (int kt = 0; kt < 32; ++kt) {
        const int cb = kt & 1;
        if (kt + 1 < 32) stageQK(kt + 1, cb ^ 1);
        const int ko = (lane >> 4) * 8;
        const bf16x8 aq = *(const bf16x8*)&Qs[cb][(w * 16 + (lane & 15)) * 32 + ko];
        #pragma unroll
        for (int n = 0; n < 6; ++n) {
            const bf16x8 bk = *(const bf16x8*)&Ks[cb][(n * 16 + (lane & 15)) * 32 + ko];
            s[n] = __builtin_amdgcn_mfma_f32_16x16x32_bf16(aq, bk, s[n], 0, 0, 0);
        }
        __syncthreads();
    }
    #pragma unroll
    for (int n = 0; n < 6; ++n)
        #pragma unroll
        for (int r = 0; r < 4; ++r)
            S_lds[w * 16 + ((lane >> 4) << 2) + r][n * 16 + (lane & 15)] = s[n][r] * 0.03125f;
    __syncthreads();

    {
        const int row = t >> 2, c0 = (t & 3) * 24;
        float e[24];
        float mx = -1e30f;
        #pragma unroll
        for (int c = 0; c < 24; ++c) {
            const int kj = c0 + c;
            const bool valid = (kj > row) && (kj <= row + 64) && (q0 - 64 + kj >= 0);
            const float sv = valid ? S_lds[row][kj] : -1e30f;
            e[c] = sv;
            mx = fmaxf(mx, sv);
        }
        mx = fmaxf(mx, __shfl_xor(mx, 1));
        mx = fmaxf(mx, __shfl_xor(mx, 2));
        float sum = 0.f;
        #pragma unroll
        for (int c = 0; c < 24; ++c) {
            const float ev = (e[c] > -1e29f) ? __expf(e[c] - mx) : 0.f;
            e[c] = ev; sum += ev;
        }
        sum += __shfl_xor(sum, 1);
        sum += __shfl_xor(sum, 2);
        const float inv = 1.f / sum;
        #pragma unroll
        for (int c = 0; c < 24; ++c)
            P_lds[row * 96 + c0 + c] = to_bf16s(e[c] * inv);
    }

    auto stageV = [&](int dc, int bf) {
        #pragma unroll
        for (int s2 = 0; s2 < 12; ++s2) {
            const int idx = s2 * 128 + t;
            const int dr = idx / 12, c = idx - dr * 12;
            int j = q0 - 64 + c * 8; if (j < 0) j = 0;
            load_lds16(VT + (long)(dc * 128 + dr) * Mtot + b * T + j, &VTs[bf][idx * 8]);
        }
    };
    stageV(0, 0);
    __syncthreads();

    bf16x8 pa[3];
    {
        const int ko = (lane >> 4) * 8;
        #pragma unroll
        for (int kc = 0; kc < 3; ++kc)
            pa[kc] = *(const bf16x8*)&P_lds[(w * 16 + (lane & 15)) * 96 + kc * 32 + ko];
    }
    for (int dc = 0; dc < 8; ++dc) {
        const int cb = dc & 1;
        if (dc + 1 < 8) stageV(dc + 1, cb ^ 1);
        f32x4 o[8] = {};
        const int ko = (lane >> 4) * 8;
        #pragma unroll
        for (int kc = 0; kc < 3; ++kc)
            #pragma unroll
            for (int n = 0; n < 8; ++n) {
                const bf16x8 vb = *(const bf16x8*)&VTs[cb][(n * 16 + (lane & 15)) * 96 + kc * 32 + ko];
                o[n] = __builtin_amdgcn_mfma_f32_16x16x32_bf16(pa[kc], vb, o[n], 0, 0, 0);
            }
        __syncthreads();
        #pragma unroll
        for (int n = 0; n < 8; ++n)
            #pragma unroll
            for (int r = 0; r < 4; ++r) {
                const long grow = qrow0 + w * 16 + ((lane >> 4) << 2) + r;
                const int gcol = dc * 128 + n * 16 + (lane & 15);
                att[grow * D + gcol] = to_bf16s(o[n][r]);
            }
    }
}

// ---------------------------------------------------------------------------
extern "C" void kernel_launch(void* const* d_in, const int* in_sizes, int n_in,
                              void* d_out, int out_size, void* d_ws, size_t ws_size,
                              hipStream_t stream) {
    const float* x   = (const float*)d_in[0];
    const float* n1w = (const float*)d_in[1];
    const float* n2w = (const float*)d_in[2];
    const float* Wq  = (const float*)d_in[3];
    const float* Wk  = (const float*)d_in[4];
    const float* Wv  = (const float*)d_in[5];
    const float* Wo  = (const float*)d_in[6];
    const float* W1  = (const float*)d_in[7];
    const float* W2  = (const float*)d_in[8];
    const float* W3  = (const float*)d_in[9];

    const int M = 8192;           // B*T
    char* ws = (char*)d_ws;
    size_t off = 0;
    auto alloc = [&](size_t bytes) { void* p = ws + off; off += (bytes + 255) & ~(size_t)255; return p; };

    short* xn1 = (short*)alloc((size_t)M * 1024 * 2);   // reused as att
    short* qk  = (short*)alloc((size_t)M * 2048 * 2);   // q | k rows (ld=2048); xn2/h alias
    short* vT  = (short*)alloc((size_t)M * 1024 * 2);   // V^T [1024][8192]
    float* x2  = (float*)alloc((size_t)M * 1024 * 4);
    short* WqT = (short*)alloc((size_t)1024 * 1024 * 2);   // WqT,WkT,WvT contiguous
    short* WkT = (short*)alloc((size_t)1024 * 1024 * 2);
    short* WvT = (short*)alloc((size_t)1024 * 1024 * 2);
    short* WoT = (short*)alloc((size_t)1024 * 1024 * 2);
    short* W13T= (short*)alloc((size_t)4096 * 1024 * 2);   // interleaved W1/W3
    short* W2T = (short*)alloc((size_t)1024 * 2048 * 2);
    short* att = xn1;                                   // xn1 dead after QKV
    short* xn2 = qk;                                    // q/k dead after attention
    short* h   = qk + (size_t)M * 1024;                 // spans qk 2nd half + vT (32MB)

    // transposes + rmsnorm1 in one launch
    prep_kernel<<<18432, 256, 0, stream>>>(Wq, Wk, Wv, Wo, W1, W3, W2,
                                           WqT, WkT, WvT, WoT, W13T, W2T,
                                           x, n1w, xn1);
    // fused QKV on the 8-phase 256^2 structure: [M,3072], grid 384
    gemm256T<5><<<384, 512, 0, stream>>>(xn1, WqT, qk, vT, M, 3072, 1024);
    // attention -> att (bf16)
    attn_kernel<<<256, 128, 0, stream>>>(qk, qk + 1024, 2048, vT, att);
    // x2 = x + att @ Wo   (fp32)
    gemm128o<<<512, 256, 0, stream>>>(att, WoT, x, x2, M, 1024, 1024);
    // norm2 -> xn2 (bf16)
    rmsnorm_kernel<<<M, 256, 0, stream>>>(x2, n2w, xn2);
    // h = silu(xn2@W1) * (xn2@W3)  — fused interleaved GEMM, N=4096
    gemm256T<6><<<512, 512, 0, stream>>>(xn2, W13T, h, nullptr, M, 4096, 1024);
    // out = x2 + h @ W2   (fp32)
    gemm128o<<<512, 256, 0, stream>>>(h, W2T, x2, (float*)d_out, M, 1024, 2048);
}

// Round 11
// 273.015 us; speedup vs baseline: 1.1368x; 1.1041x over previous
//
#include <hip/hip_runtime.h>
#include <hip/hip_bf16.h>

typedef __attribute__((ext_vector_type(8))) short bf16x8;
typedef __attribute__((ext_vector_type(4))) float f32x4;

__device__ __forceinline__ short to_bf16s(float f) {
    union { __hip_bfloat16 h; short s; } u;
    u.h = __float2bfloat16(f);
    return u.s;
}

__device__ __forceinline__ void load_lds16(const void* g, void* l) {
    __builtin_amdgcn_global_load_lds((const __attribute__((address_space(1))) void*)g,
                                     (__attribute__((address_space(3))) void*)l, 16, 0, 0);
}

// ---------------------------------------------------------------------------
// prep: blocks [0,10240): weight transposes (fp32 [K][N] -> bf16 [N][K]),
// W1/W3 column-interleaved into W13T[4096][1024].  Blocks [10240,18432):
// rmsnorm1 row (bid-10240) -> xn1 bf16.
// ---------------------------------------------------------------------------
__global__ __launch_bounds__(256)
void prep_kernel(const float* __restrict__ Wq, const float* __restrict__ Wk,
                 const float* __restrict__ Wv, const float* __restrict__ Wo,
                 const float* __restrict__ W1, const float* __restrict__ W3,
                 const float* __restrict__ W2,
                 short* __restrict__ WqT, short* __restrict__ WkT,
                 short* __restrict__ WvT, short* __restrict__ WoT,
                 short* __restrict__ W13T, short* __restrict__ W2T,
                 const float* __restrict__ x, const float* __restrict__ n1w,
                 short* __restrict__ xn1) {
    const int bid = blockIdx.x;
    const int t = threadIdx.x;
    if (bid >= 10240) {
        const long row = bid - 10240;
        float4 v = ((const float4*)(x + row * 1024))[t];
        float ss = v.x * v.x + v.y * v.y + v.z * v.z + v.w * v.w;
        #pragma unroll
        for (int off = 32; off; off >>= 1) ss += __shfl_xor(ss, off);
        __shared__ float red[4];
        if ((t & 63) == 0) red[t >> 6] = ss;
        __syncthreads();
        ss = red[0] + red[1] + red[2] + red[3];
        const float inv = rsqrtf(ss * (1.0f / 1024.0f) + 1e-6f);
        float4 wv = ((const float4*)n1w)[t];
        short4 o;
        o.x = to_bf16s(v.x * inv * wv.x);
        o.y = to_bf16s(v.y * inv * wv.y);
        o.z = to_bf16s(v.z * inv * wv.z);
        o.w = to_bf16s(v.w * inv * wv.w);
        *(short4*)&xn1[row * 1024 + t * 4] = o;
        return;
    }
    __shared__ float tile[32][33];
    const float* src; short* dst; int K, N, tl, rs = 1, ro = 0;
    if (bid < 4096) {
        const int wi = bid >> 10; tl = bid & 1023;
        src = wi == 0 ? Wq : wi == 1 ? Wk : wi == 2 ? Wv : Wo;
        dst = wi == 0 ? WqT : wi == 1 ? WkT : wi == 2 ? WvT : WoT;
        K = 1024; N = 1024;
    } else if (bid < 8192) {
        const int wi = (bid - 4096) >> 11; tl = (bid - 4096) & 2047;
        src = wi ? W3 : W1; dst = W13T; rs = 2; ro = wi;
        K = 1024; N = 2048;
    } else {
        tl = bid - 8192; src = W2; dst = W2T;
        K = 2048; N = 1024;
    }
    const int nx = N >> 5;
    const int n0 = (tl % nx) * 32, k0 = (tl / nx) * 32;
    {
        const int lr = t >> 3, lc = (t & 7) * 4;
        float4 v = *(const float4*)&src[(long)(k0 + lr) * N + n0 + lc];
        tile[lr][lc] = v.x; tile[lr][lc + 1] = v.y;
        tile[lr][lc + 2] = v.z; tile[lr][lc + 3] = v.w;
    }
    __syncthreads();
    {
        const int nr = t >> 3, kc = (t & 7) * 4;
        short4 o;
        o.x = to_bf16s(tile[kc][nr]);
        o.y = to_bf16s(tile[kc + 1][nr]);
        o.z = to_bf16s(tile[kc + 2][nr]);
        o.w = to_bf16s(tile[kc + 3][nr]);
        *(short4*)&dst[(long)((n0 + nr) * rs + ro) * K + k0 + kc] = o;
    }
}

// ---------------------------------------------------------------------------
// RMSNorm (fp32 in) -> bf16 out.  One block per row, D=1024.  (norm2)
// ---------------------------------------------------------------------------
__global__ __launch_bounds__(256)
void rmsnorm_kernel(const float* __restrict__ x, const float* __restrict__ wt,
                    short* __restrict__ out) {
    const long row = blockIdx.x;
    const int t = threadIdx.x;
    float4 v = ((const float4*)(x + row * 1024))[t];
    float ss = v.x * v.x + v.y * v.y + v.z * v.z + v.w * v.w;
    #pragma unroll
    for (int off = 32; off; off >>= 1) ss += __shfl_xor(ss, off);
    __shared__ float red[4];
    if ((t & 63) == 0) red[t >> 6] = ss;
    __syncthreads();
    ss = red[0] + red[1] + red[2] + red[3];
    const float inv = rsqrtf(ss * (1.0f / 1024.0f) + 1e-6f);
    float4 wv = ((const float4*)wt)[t];
    short4 o;
    o.x = to_bf16s(v.x * inv * wv.x);
    o.y = to_bf16s(v.y * inv * wv.y);
    o.z = to_bf16s(v.z * inv * wv.z);
    o.w = to_bf16s(v.w * inv * wv.w);
    *(short4*)&out[row * 1024 + t * 4] = o;
}

// ---------------------------------------------------------------------------
// MFMA phase macro (barrier ; lgkm ; setprio ; 16 MFMA ; barrier).
// ---------------------------------------------------------------------------
#define MFMA16(MB, NB, BREG)                                                   \
    __builtin_amdgcn_s_barrier();                                              \
    asm volatile("s_waitcnt lgkmcnt(0)");                                      \
    __builtin_amdgcn_s_setprio(1);                                             \
    _Pragma("unroll")                                                          \
    for (int m_ = 0; m_ < 4; ++m_)                                             \
        _Pragma("unroll")                                                      \
        for (int n_ = 0; n_ < 2; ++n_) {                                       \
            acc[(MB) + m_][(NB) + n_] = __builtin_amdgcn_mfma_f32_16x16x32_bf16( \
                a[m_][0], BREG[n_][0], acc[(MB) + m_][(NB) + n_], 0, 0, 0);    \
            acc[(MB) + m_][(NB) + n_] = __builtin_amdgcn_mfma_f32_16x16x32_bf16( \
                a[m_][1], BREG[n_][1], acc[(MB) + m_][(NB) + n_], 0, 0, 0);    \
        }                                                                      \
    __builtin_amdgcn_s_setprio(0);                                             \
    __builtin_amdgcn_s_barrier();

// ---------------------------------------------------------------------------
// gemm256T: 256x256 tile, BK=64, 8 waves (2x4) of 128x64, 2-buf dbuf (128K),
// m201-style 8-phase schedule, vmcnt(4) checkpoints (verified @758TF).
// EPI 5: bf16 outp[row][2048] (ld 2048) — used for QK (N=2048, all gcol<2048).
// EPI 6: fused SwiGLU over column-interleaved B (even gcol = W1 col, odd =
//        W3 col): outp[row][gcol/2] = silu(C_even) * C_odd.
// ---------------------------------------------------------------------------
#define RA2(BUF, MG)                                                           \
    _Pragma("unroll")                                                          \
    for (int m_ = 0; m_ < 4; ++m_) {                                           \
        const int rb_ = ((BUF) * 2 + wr) * 16384 + (((MG) * 4 + m_) * 16 + lm) * 128; \
        a[m_][0] = *(const bf16x8*)&lds[rb_ + ((lk * 16) ^ sw)];               \
        a[m_][1] = *(const bf16x8*)&lds[rb_ + ((64 + lk * 16) ^ sw)];          \
    }
#define RB2(BUF, NH, ARR)                                                      \
    _Pragma("unroll")                                                          \
    for (int n_ = 0; n_ < 2; ++n_) {                                           \
        const int rb_ = 65536 + ((BUF) * 2 + (wc >> 1)) * 16384 +              \
                        ((wc & 1) * 64 + ((NH) * 2 + n_) * 16 + lm) * 128;     \
        ARR[n_][0] = *(const bf16x8*)&lds[rb_ + ((lk * 16) ^ sw)];             \
        ARR[n_][1] = *(const bf16x8*)&lds[rb_ + ((64 + lk * 16) ^ sw)];        \
    }

template<int EPI>
__global__ __launch_bounds__(512, 2)
void gemm256T(const short* __restrict__ A, const short* __restrict__ B0,
              short* __restrict__ outp, int M, int N, int K) {
    __shared__ __align__(16) char lds[131072];

    const int t = threadIdx.x;
    const int lane = t & 63, w = t >> 6;
    const int wr = w >> 2, wc = w & 3;
    const int lm = lane & 15, lk = lane >> 4;
    const int sw = (lm & 7) << 4;

    const int nbn = N >> 8;
    const int chunk = gridDim.x >> 3;
    const int logical = (blockIdx.x & 7) * chunk + (blockIdx.x >> 3);
    const int bm = logical / nbn, bn = logical - (logical / nbn) * nbn;

    const long Kb = (long)K * 2;
    const char* Ab = (const char*)A;
    const char* Bb = (const char*)B0;

    long srcA[2][2], srcB[2][2];
    {
        const int rowp = t >> 3;
        const int cbx = (t & 7) * 16;
        const int swz = ((t >> 3) & 7) << 4;
        #pragma unroll
        for (int h = 0; h < 2; ++h)
            #pragma unroll
            for (int c = 0; c < 2; ++c) {
                srcA[h][c] = (long)(bm * 256 + h * 128 + c * 64 + rowp) * Kb + (cbx ^ swz);
                srcB[h][c] = (long)(bn * 256 + h * 128 + c * 64 + rowp) * Kb + (cbx ^ swz);
            }
    }
    auto stA = [&](int kt, int h) {
        const int buf = kt & 1;
        #pragma unroll
        for (int c = 0; c < 2; ++c)
            load_lds16(Ab + srcA[h][c] + (long)kt * 128,
                       &lds[(buf * 2 + h) * 16384 + c * 8192 + t * 16]);
    };
    auto stB = [&](int kt, int h) {
        const int buf = kt & 1;
        #pragma unroll
        for (int c = 0; c < 2; ++c)
            load_lds16(Bb + srcB[h][c] + (long)kt * 128,
                       &lds[65536 + (buf * 2 + h) * 16384 + c * 8192 + t * 16]);
    };

    f32x4 acc[8][4] = {};
    bf16x8 a[4][2], b0[2][2], b1[2][2];
    const int nt = K >> 6;

    stB(0, 0); stB(0, 1); stA(0, 0); stA(0, 1); stB(1, 0); stB(1, 1);
    asm volatile("s_waitcnt vmcnt(4)" ::: "memory");
    __builtin_amdgcn_s_barrier();

    for (int u = 0; u < nt; u += 2) {
        const bool pf = (u + 2) < nt;
        RA2(0, 0); RB2(0, 0, b0);
        stA(u + 1, 0);
        MFMA16(0, 0, b0)
        RB2(0, 1, b1);
        stA(u + 1, 1);
        MFMA16(0, 2, b1)
        RA2(0, 1);
        if (pf) stB(u + 2, 0);
        MFMA16(4, 2, b1)
        if (pf) { stB(u + 2, 1); asm volatile("s_waitcnt vmcnt(4)" ::: "memory"); }
        else    { asm volatile("s_waitcnt vmcnt(0)" ::: "memory"); }
        MFMA16(4, 0, b0)
        RA2(1, 0); RB2(1, 0, b0);
        if (pf) stA(u + 2, 0);
        MFMA16(0, 0, b0)
        RB2(1, 1, b1);
        if (pf) stA(u + 2, 1);
        MFMA16(0, 2, b1)
        RA2(1, 1);
        if (pf) stB(u + 3, 0);
        MFMA16(4, 2, b1)
        if (pf) { stB(u + 3, 1); asm volatile("s_waitcnt vmcnt(4)" ::: "memory"); }
        else    { asm volatile("s_waitcnt vmcnt(0)" ::: "memory"); }
        MFMA16(4, 0, b0)
    }

    const int NH = N >> 1;
    #pragma unroll
    for (int mf = 0; mf < 8; ++mf)
      #pragma unroll
      for (int nf = 0; nf < 4; ++nf)
        #pragma unroll
        for (int r = 0; r < 4; ++r) {
            const int grow = bm * 256 + wr * 128 + mf * 16 + lk * 4 + r;
            const int gcol = bn * 256 + wc * 64 + nf * 16 + lm;
            const float v = acc[mf][nf][r];
            if constexpr (EPI == 5) {
                outp[(long)grow * 2048 + gcol] = to_bf16s(v);
            } else {   // EPI 6: SwiGLU pair via lane-xor
                const float g3 = __shfl_xor(v, 1);
                if (!(lane & 1)) {
                    const float sws = v / (1.f + __expf(-v));
                    outp[(long)grow * NH + (gcol >> 1)] = to_bf16s(sws * g3);
                }
            }
        }
}

// ---------------------------------------------------------------------------
// gemm128T: 128x128 tile, BK=64, 256 threads (4 waves 2x2, wave 64x64),
// 64 KiB LDS dbuf -> 2 blocks/CU.  Plain stage->read->MFMA->syncthreads loop,
// swizzled LDS, XCD chunking.  (round-7 verified)
// EPI 2: fp32 out = res + C.     EPI 8: bf16 transposed out vT[gcol][8192].
// ---------------------------------------------------------------------------
template<int EPI>
__global__ __launch_bounds__(256, 2)
void gemm128T(const short* __restrict__ A, const short* __restrict__ B0,
              const float* __restrict__ res, float* __restrict__ outp,
              short* __restrict__ outp2, int M, int N, int K) {
    __shared__ __align__(16) char lds[65536];   // A: 2x16K @0, B: 2x16K @32768

    const int t = threadIdx.x;
    const int lane = t & 63, w = t >> 6;
    const int wr = w >> 1, wc = w & 1;
    const int lm = lane & 15, lk = lane >> 4;
    const int sw = (lm & 7) << 4;

    const int nbn = N >> 7;
    const int chunk = gridDim.x >> 3;
    const int logical = (blockIdx.x & 7) * chunk + (blockIdx.x >> 3);
    const int bm = logical / nbn, bn = logical - (logical / nbn) * nbn;

    const long Kb = (long)K * 2;
    const char* Ab = (const char*)A;
    const char* Bb = (const char*)B0;

    long srcA[4], srcB[4];
    {
        const int rowp = t >> 3;                 // + c*32
        const int cbx = (t & 7) * 16;
        const int swz = ((t >> 3) & 7) << 4;
        #pragma unroll
        for (int c = 0; c < 4; ++c) {
            srcA[c] = (long)(bm * 128 + c * 32 + rowp) * Kb + (cbx ^ swz);
            srcB[c] = (long)(bn * 128 + c * 32 + rowp) * Kb + (cbx ^ swz);
        }
    }
    auto stage = [&](int kt, int buf) {
        #pragma unroll
        for (int c = 0; c < 4; ++c)
            load_lds16(Ab + srcA[c] + (long)kt * 128,
                       &lds[buf * 16384 + c * 4096 + t * 16]);
        #pragma unroll
        for (int c = 0; c < 4; ++c)
            load_lds16(Bb + srcB[c] + (long)kt * 128,
                       &lds[32768 + buf * 16384 + c * 4096 + t * 16]);
    };

    f32x4 acc[4][4] = {};
    const int nt = K >> 6;

    stage(0, 0);
    asm volatile("s_waitcnt vmcnt(0)" ::: "memory");
    __syncthreads();

    for (int kt = 0; kt < nt; ++kt) {
        const int buf = kt & 1;
        if (kt + 1 < nt) stage(kt + 1, buf ^ 1);
        bf16x8 a[4][2], b[4][2];
        #pragma unroll
        for (int m = 0; m < 4; ++m) {
            const int rb = buf * 16384 + (wr * 64 + m * 16 + lm) * 128;
            a[m][0] = *(const bf16x8*)&lds[rb + ((lk * 16) ^ sw)];
            a[m][1] = *(const bf16x8*)&lds[rb + ((64 + lk * 16) ^ sw)];
        }
        #pragma unroll
        for (int n = 0; n < 4; ++n) {
            const int rb = 32768 + buf * 16384 + (wc * 64 + n * 16 + lm) * 128;
            b[n][0] = *(const bf16x8*)&lds[rb + ((lk * 16) ^ sw)];
            b[n][1] = *(const bf16x8*)&lds[rb + ((64 + lk * 16) ^ sw)];
        }
        #pragma unroll
        for (int m = 0; m < 4; ++m)
            #pragma unroll
            for (int n = 0; n < 4; ++n) {
                acc[m][n] = __builtin_amdgcn_mfma_f32_16x16x32_bf16(a[m][0], b[n][0], acc[m][n], 0, 0, 0);
                acc[m][n] = __builtin_amdgcn_mfma_f32_16x16x32_bf16(a[m][1], b[n][1], acc[m][n], 0, 0, 0);
            }
        __syncthreads();
    }

    #pragma unroll
    for (int m = 0; m < 4; ++m)
      #pragma unroll
      for (int n = 0; n < 4; ++n)
        #pragma unroll
        for (int r = 0; r < 4; ++r) {
            const int grow = bm * 128 + wr * 64 + m * 16 + lk * 4 + r;
            const int gcol = bn * 128 + wc * 64 + n * 16 + lm;
            if constexpr (EPI == 2) {
                const long i = (long)grow * N + gcol;
                outp[i] = res[i] + acc[m][n][r];
            } else {  // EPI 8: transposed bf16 (V^T)
                outp2[(long)gcol * 8192 + grow] = to_bf16s(acc[m][n][r]);
            }
        }
}

// ---------------------------------------------------------------------------
// Windowed causal attention (verified): dbuf staging, 32 q/block.
// ---------------------------------------------------------------------------
__global__ __launch_bounds__(128)
void attn_kernel(const short* __restrict__ Q, const short* __restrict__ Km,
                 int ldq, const short* __restrict__ VT, short* __restrict__ att) {
    const int T = 2048, D = 1024, Mtot = 8192;
    const int bid = blockIdx.x;
    const int b = bid >> 6;
    const int q0 = (bid & 63) << 5;
    const long qrow0 = (long)b * T + q0;
    const int t = threadIdx.x, lane = t & 63, w = t >> 6;

    __shared__ short Qs[2][32 * 32];
    __shared__ short Ks[2][96 * 32];
    __shared__ float S_lds[32][100];
    __shared__ short P_lds[32 * 96];
    __shared__ short VTs[2][128 * 96];

    const int trow = t >> 2, tk8 = (t & 3) * 8;
    auto stageQK = [&](int kt, int bf) {
        const int k0 = kt << 5;
        load_lds16(Q + (qrow0 + trow) * ldq + k0 + tk8, &Qs[bf][t * 8]);
        #pragma unroll
        for (int s2 = 0; s2 < 3; ++s2) {
            const int krow = s2 * 32 + trow;
            int j = q0 - 64 + krow; if (j < 0) j = 0;
            load_lds16(Km + ((long)b * T + j) * ldq + k0 + tk8, &Ks[bf][(s2 * 128 + t) * 8]);
        }
    };

    f32x4 s[6] = {};
    stageQK(0, 0);
    __syncthreads();
    for (int kt = 0; kt < 32; ++kt) {
        const int cb = kt & 1;
        if (kt + 1 < 32) stageQK(kt + 1, cb ^ 1);
        const int ko = (lane >> 4) * 8;
        const bf16x8 aq = *(const bf16x8*)&Qs[cb][(w * 16 + (lane & 15)) * 32 + ko];
        #pragma unroll
        for (int n = 0; n < 6; ++n) {
            const bf16x8 bk = *(const bf16x8*)&Ks[cb][(n * 16 + (lane & 15)) * 32 + ko];
            s[n] = __builtin_amdgcn_mfma_f32_16x16x32_bf16(aq, bk, s[n], 0, 0, 0);
        }
        __syncthreads();
    }
    #pragma unroll
    for (int n = 0; n < 6; ++n)
        #pragma unroll
        for (int r = 0; r < 4; ++r)
            S_lds[w * 16 + ((lane >> 4) << 2) + r][n * 16 + (lane & 15)] = s[n][r] * 0.03125f;
    __syncthreads();

    {
        const int row = t >> 2, c0 = (t & 3) * 24;
        float e[24];
        float mx = -1e30f;
        #pragma unroll
        for (int c = 0; c < 24; ++c) {
            const int kj = c0 + c;
            const bool valid = (kj > row) && (kj <= row + 64) && (q0 - 64 + kj >= 0);
            const float sv = valid ? S_lds[row][kj] : -1e30f;
            e[c] = sv;
            mx = fmaxf(mx, sv);
        }
        mx = fmaxf(mx, __shfl_xor(mx, 1));
        mx = fmaxf(mx, __shfl_xor(mx, 2));
        float sum = 0.f;
        #pragma unroll
        for (int c = 0; c < 24; ++c) {
            const float ev = (e[c] > -1e29f) ? __expf(e[c] - mx) : 0.f;
            e[c] = ev; sum += ev;
        }
        sum += __shfl_xor(sum, 1);
        sum += __shfl_xor(sum, 2);
        const float inv = 1.f / sum;
        #pragma unroll
        for (int c = 0; c < 24; ++c)
            P_lds[row * 96 + c0 + c] = to_bf16s(e[c] * inv);
    }

    auto stageV = [&](int dc, int bf) {
        #pragma unroll
        for (int s2 = 0; s2 < 12; ++s2) {
            const int idx = s2 * 128 + t;
            const int dr = idx / 12, c = idx - dr * 12;
            int j = q0 - 64 + c * 8; if (j < 0) j = 0;
            load_lds16(VT + (long)(dc * 128 + dr) * Mtot + b * T + j, &VTs[bf][idx * 8]);
        }
    };
    stageV(0, 0);
    __syncthreads();

    bf16x8 pa[3];
    {
        const int ko = (lane >> 4) * 8;
        #pragma unroll
        for (int kc = 0; kc < 3; ++kc)
            pa[kc] = *(const bf16x8*)&P_lds[(w * 16 + (lane & 15)) * 96 + kc * 32 + ko];
    }
    for (int dc = 0; dc < 8; ++dc) {
        const int cb = dc & 1;
        if (dc + 1 < 8) stageV(dc + 1, cb ^ 1);
        f32x4 o[8] = {};
        const int ko = (lane >> 4) * 8;
        #pragma unroll
        for (int kc = 0; kc < 3; ++kc)
            #pragma unroll
            for (int n = 0; n < 8; ++n) {
                const bf16x8 vb = *(const bf16x8*)&VTs[cb][(n * 16 + (lane & 15)) * 96 + kc * 32 + ko];
                o[n] = __builtin_amdgcn_mfma_f32_16x16x32_bf16(pa[kc], vb, o[n], 0, 0, 0);
            }
        __syncthreads();
        #pragma unroll
        for (int n = 0; n < 8; ++n)
            #pragma unroll
            for (int r = 0; r < 4; ++r) {
                const long grow = qrow0 + w * 16 + ((lane >> 4) << 2) + r;
                const int gcol = dc * 128 + n * 16 + (lane & 15);
                att[grow * D + gcol] = to_bf16s(o[n][r]);
            }
    }
}

// ---------------------------------------------------------------------------
extern "C" void kernel_launch(void* const* d_in, const int* in_sizes, int n_in,
                              void* d_out, int out_size, void* d_ws, size_t ws_size,
                              hipStream_t stream) {
    const float* x   = (const float*)d_in[0];
    const float* n1w = (const float*)d_in[1];
    const float* n2w = (const float*)d_in[2];
    const float* Wq  = (const float*)d_in[3];
    const float* Wk  = (const float*)d_in[4];
    const float* Wv  = (const float*)d_in[5];
    const float* Wo  = (const float*)d_in[6];
    const float* W1  = (const float*)d_in[7];
    const float* W2  = (const float*)d_in[8];
    const float* W3  = (const float*)d_in[9];

    const int M = 8192;           // B*T
    char* ws = (char*)d_ws;
    size_t off = 0;
    auto alloc = [&](size_t bytes) { void* p = ws + off; off += (bytes + 255) & ~(size_t)255; return p; };

    short* xn1 = (short*)alloc((size_t)M * 1024 * 2);   // reused as att
    short* qk  = (short*)alloc((size_t)M * 2048 * 2);   // q | k rows (ld=2048); xn2/h alias
    short* vT  = (short*)alloc((size_t)M * 1024 * 2);   // V^T [1024][8192]
    float* x2  = (float*)alloc((size_t)M * 1024 * 4);
    short* WqT = (short*)alloc((size_t)1024 * 1024 * 2);   // WqT,WkT contiguous = QK weight
    short* WkT = (short*)alloc((size_t)1024 * 1024 * 2);
    short* WvT = (short*)alloc((size_t)1024 * 1024 * 2);
    short* WoT = (short*)alloc((size_t)1024 * 1024 * 2);
    short* W13T= (short*)alloc((size_t)4096 * 1024 * 2);   // interleaved W1/W3
    short* W2T = (short*)alloc((size_t)1024 * 2048 * 2);
    short* att = xn1;                                   // xn1 dead after QKV
    short* xn2 = qk;                                    // q/k dead after attention
    short* h   = qk + (size_t)M * 1024;                 // spans qk 2nd half + vT (32MB)

    // transposes + rmsnorm1 in one launch
    prep_kernel<<<18432, 256, 0, stream>>>(Wq, Wk, Wv, Wo, W1, W3, W2,
                                           WqT, WkT, WvT, WoT, W13T, W2T,
                                           x, n1w, xn1);
    // QK: [M,2048] on the 8-phase 256^2 structure, grid 256 = exactly 1 round
    gemm256T<5><<<256, 512, 0, stream>>>(xn1, WqT, qk, M, 2048, 1024);
    // V^T: [M,1024] transposed out on the 2-blocks/CU 128^2 structure, grid 512
    gemm128T<8><<<512, 256, 0, stream>>>(xn1, WvT, nullptr, nullptr, vT, M, 1024, 1024);
    // attention -> att (bf16)
    attn_kernel<<<256, 128, 0, stream>>>(qk, qk + 1024, 2048, vT, att);
    // x2 = x + att @ Wo   (fp32)
    gemm128T<2><<<512, 256, 0, stream>>>(att, WoT, x, x2, nullptr, M, 1024, 1024);
    // norm2 -> xn2 (bf16)
    rmsnorm_kernel<<<M, 256, 0, stream>>>(x2, n2w, xn2);
    // h = silu(xn2@W1) * (xn2@W3)  — fused interleaved GEMM, N=4096, grid 512
    gemm256T<6><<<512, 512, 0, stream>>>(xn2, W13T, h, M, 4096, 1024);
    // out = x2 + h @ W2   (fp32)
    gemm128T<2><<<512, 256, 0, stream>>>(h, W2T, x2, (float*)d_out, nullptr, M, 1024, 2048);
}

// Round 12
// 271.940 us; speedup vs baseline: 1.1413x; 1.0040x over previous
//
#include <hip/hip_runtime.h>
#include <hip/hip_bf16.h>

typedef __attribute__((ext_vector_type(8))) short bf16x8;
typedef __attribute__((ext_vector_type(4))) float f32x4;

__device__ __forceinline__ short to_bf16s(float f) {
    union { __hip_bfloat16 h; short s; } u;
    u.h = __float2bfloat16(f);
    return u.s;
}

__device__ __forceinline__ void load_lds16(const void* g, void* l) {
    __builtin_amdgcn_global_load_lds((const __attribute__((address_space(1))) void*)g,
                                     (__attribute__((address_space(3))) void*)l, 16, 0, 0);
}

// ---------------------------------------------------------------------------
// prep: blocks [0,10240): weight transposes (fp32 [K][N] -> bf16 [N][K]),
// W1/W3 column-interleaved into W13T[4096][1024].  Blocks [10240,18432):
// rmsnorm1 row (bid-10240) -> xn1 bf16.
// ---------------------------------------------------------------------------
__global__ __launch_bounds__(256)
void prep_kernel(const float* __restrict__ Wq, const float* __restrict__ Wk,
                 const float* __restrict__ Wv, const float* __restrict__ Wo,
                 const float* __restrict__ W1, const float* __restrict__ W3,
                 const float* __restrict__ W2,
                 short* __restrict__ WqT, short* __restrict__ WkT,
                 short* __restrict__ WvT, short* __restrict__ WoT,
                 short* __restrict__ W13T, short* __restrict__ W2T,
                 const float* __restrict__ x, const float* __restrict__ n1w,
                 short* __restrict__ xn1) {
    const int bid = blockIdx.x;
    const int t = threadIdx.x;
    if (bid >= 10240) {
        const long row = bid - 10240;
        float4 v = ((const float4*)(x + row * 1024))[t];
        float ss = v.x * v.x + v.y * v.y + v.z * v.z + v.w * v.w;
        #pragma unroll
        for (int off = 32; off; off >>= 1) ss += __shfl_xor(ss, off);
        __shared__ float red[4];
        if ((t & 63) == 0) red[t >> 6] = ss;
        __syncthreads();
        ss = red[0] + red[1] + red[2] + red[3];
        const float inv = rsqrtf(ss * (1.0f / 1024.0f) + 1e-6f);
        float4 wv = ((const float4*)n1w)[t];
        short4 o;
        o.x = to_bf16s(v.x * inv * wv.x);
        o.y = to_bf16s(v.y * inv * wv.y);
        o.z = to_bf16s(v.z * inv * wv.z);
        o.w = to_bf16s(v.w * inv * wv.w);
        *(short4*)&xn1[row * 1024 + t * 4] = o;
        return;
    }
    __shared__ float tile[32][33];
    const float* src; short* dst; int K, N, tl, rs = 1, ro = 0;
    if (bid < 4096) {
        const int wi = bid >> 10; tl = bid & 1023;
        src = wi == 0 ? Wq : wi == 1 ? Wk : wi == 2 ? Wv : Wo;
        dst = wi == 0 ? WqT : wi == 1 ? WkT : wi == 2 ? WvT : WoT;
        K = 1024; N = 1024;
    } else if (bid < 8192) {
        const int wi = (bid - 4096) >> 11; tl = (bid - 4096) & 2047;
        src = wi ? W3 : W1; dst = W13T; rs = 2; ro = wi;
        K = 1024; N = 2048;
    } else {
        tl = bid - 8192; src = W2; dst = W2T;
        K = 2048; N = 1024;
    }
    const int nx = N >> 5;
    const int n0 = (tl % nx) * 32, k0 = (tl / nx) * 32;
    {
        const int lr = t >> 3, lc = (t & 7) * 4;
        float4 v = *(const float4*)&src[(long)(k0 + lr) * N + n0 + lc];
        tile[lr][lc] = v.x; tile[lr][lc + 1] = v.y;
        tile[lr][lc + 2] = v.z; tile[lr][lc + 3] = v.w;
    }
    __syncthreads();
    {
        const int nr = t >> 3, kc = (t & 7) * 4;
        short4 o;
        o.x = to_bf16s(tile[kc][nr]);
        o.y = to_bf16s(tile[kc + 1][nr]);
        o.z = to_bf16s(tile[kc + 2][nr]);
        o.w = to_bf16s(tile[kc + 3][nr]);
        *(short4*)&dst[(long)((n0 + nr) * rs + ro) * K + k0 + kc] = o;
    }
}

// ---------------------------------------------------------------------------
// RMSNorm (fp32 in) -> bf16 out.  One block per row, D=1024.  (norm2)
// ---------------------------------------------------------------------------
__global__ __launch_bounds__(256)
void rmsnorm_kernel(const float* __restrict__ x, const float* __restrict__ wt,
                    short* __restrict__ out) {
    const long row = blockIdx.x;
    const int t = threadIdx.x;
    float4 v = ((const float4*)(x + row * 1024))[t];
    float ss = v.x * v.x + v.y * v.y + v.z * v.z + v.w * v.w;
    #pragma unroll
    for (int off = 32; off; off >>= 1) ss += __shfl_xor(ss, off);
    __shared__ float red[4];
    if ((t & 63) == 0) red[t >> 6] = ss;
    __syncthreads();
    ss = red[0] + red[1] + red[2] + red[3];
    const float inv = rsqrtf(ss * (1.0f / 1024.0f) + 1e-6f);
    float4 wv = ((const float4*)wt)[t];
    short4 o;
    o.x = to_bf16s(v.x * inv * wv.x);
    o.y = to_bf16s(v.y * inv * wv.y);
    o.z = to_bf16s(v.z * inv * wv.z);
    o.w = to_bf16s(v.w * inv * wv.w);
    *(short4*)&out[row * 1024 + t * 4] = o;
}

// ---------------------------------------------------------------------------
// MFMA phase macro (barrier ; lgkm ; setprio ; 16 MFMA ; barrier).
// ---------------------------------------------------------------------------
#define MFMA16(MB, NB, BREG)                                                   \
    __builtin_amdgcn_s_barrier();                                              \
    asm volatile("s_waitcnt lgkmcnt(0)");                                      \
    __builtin_amdgcn_s_setprio(1);                                             \
    _Pragma("unroll")                                                          \
    for (int m_ = 0; m_ < 4; ++m_)                                             \
        _Pragma("unroll")                                                      \
        for (int n_ = 0; n_ < 2; ++n_) {                                       \
            acc[(MB) + m_][(NB) + n_] = __builtin_amdgcn_mfma_f32_16x16x32_bf16( \
                a[m_][0], BREG[n_][0], acc[(MB) + m_][(NB) + n_], 0, 0, 0);    \
            acc[(MB) + m_][(NB) + n_] = __builtin_amdgcn_mfma_f32_16x16x32_bf16( \
                a[m_][1], BREG[n_][1], acc[(MB) + m_][(NB) + n_], 0, 0, 0);    \
        }                                                                      \
    __builtin_amdgcn_s_setprio(0);                                             \
    __builtin_amdgcn_s_barrier();

// ---------------------------------------------------------------------------
// gemm256T: 256x256 tile, BK=64, 8 waves (2x4) of 128x64, 2-buf dbuf (128K),
// m201-style 8-phase schedule, vmcnt(4) checkpoints (verified @758TF).
// EPI 5: bf16 outp[row][2048] (ld 2048) — used for QK (N=2048, all gcol<2048).
// EPI 6: fused SwiGLU over column-interleaved B (even gcol = W1 col, odd =
//        W3 col): outp[row][gcol/2] = silu(C_even) * C_odd.
// ---------------------------------------------------------------------------
#define RA2(BUF, MG)                                                           \
    _Pragma("unroll")                                                          \
    for (int m_ = 0; m_ < 4; ++m_) {                                           \
        const int rb_ = ((BUF) * 2 + wr) * 16384 + (((MG) * 4 + m_) * 16 + lm) * 128; \
        a[m_][0] = *(const bf16x8*)&lds[rb_ + ((lk * 16) ^ sw)];               \
        a[m_][1] = *(const bf16x8*)&lds[rb_ + ((64 + lk * 16) ^ sw)];          \
    }
#define RB2(BUF, NH, ARR)                                                      \
    _Pragma("unroll")                                                          \
    for (int n_ = 0; n_ < 2; ++n_) {                                           \
        const int rb_ = 65536 + ((BUF) * 2 + (wc >> 1)) * 16384 +              \
                        ((wc & 1) * 64 + ((NH) * 2 + n_) * 16 + lm) * 128;     \
        ARR[n_][0] = *(const bf16x8*)&lds[rb_ + ((lk * 16) ^ sw)];             \
        ARR[n_][1] = *(const bf16x8*)&lds[rb_ + ((64 + lk * 16) ^ sw)];        \
    }

template<int EPI>
__global__ __launch_bounds__(512, 2)
void gemm256T(const short* __restrict__ A, const short* __restrict__ B0,
              short* __restrict__ outp, int M, int N, int K) {
    __shared__ __align__(16) char lds[131072];

    const int t = threadIdx.x;
    const int lane = t & 63, w = t >> 6;
    const int wr = w >> 2, wc = w & 3;
    const int lm = lane & 15, lk = lane >> 4;
    const int sw = (lm & 7) << 4;

    const int nbn = N >> 8;
    const int chunk = gridDim.x >> 3;
    const int logical = (blockIdx.x & 7) * chunk + (blockIdx.x >> 3);
    const int bm = logical / nbn, bn = logical - (logical / nbn) * nbn;

    const long Kb = (long)K * 2;
    const char* Ab = (const char*)A;
    const char* Bb = (const char*)B0;

    long srcA[2][2], srcB[2][2];
    {
        const int rowp = t >> 3;
        const int cbx = (t & 7) * 16;
        const int swz = ((t >> 3) & 7) << 4;
        #pragma unroll
        for (int h = 0; h < 2; ++h)
            #pragma unroll
            for (int c = 0; c < 2; ++c) {
                srcA[h][c] = (long)(bm * 256 + h * 128 + c * 64 + rowp) * Kb + (cbx ^ swz);
                srcB[h][c] = (long)(bn * 256 + h * 128 + c * 64 + rowp) * Kb + (cbx ^ swz);
            }
    }
    auto stA = [&](int kt, int h) {
        const int buf = kt & 1;
        #pragma unroll
        for (int c = 0; c < 2; ++c)
            load_lds16(Ab + srcA[h][c] + (long)kt * 128,
                       &lds[(buf * 2 + h) * 16384 + c * 8192 + t * 16]);
    };
    auto stB = [&](int kt, int h) {
        const int buf = kt & 1;
        #pragma unroll
        for (int c = 0; c < 2; ++c)
            load_lds16(Bb + srcB[h][c] + (long)kt * 128,
                       &lds[65536 + (buf * 2 + h) * 16384 + c * 8192 + t * 16]);
    };

    f32x4 acc[8][4] = {};
    bf16x8 a[4][2], b0[2][2], b1[2][2];
    const int nt = K >> 6;

    stB(0, 0); stB(0, 1); stA(0, 0); stA(0, 1); stB(1, 0); stB(1, 1);
    asm volatile("s_waitcnt vmcnt(4)" ::: "memory");
    __builtin_amdgcn_s_barrier();

    for (int u = 0; u < nt; u += 2) {
        const bool pf = (u + 2) < nt;
        RA2(0, 0); RB2(0, 0, b0);
        stA(u + 1, 0);
        MFMA16(0, 0, b0)
        RB2(0, 1, b1);
        stA(u + 1, 1);
        MFMA16(0, 2, b1)
        RA2(0, 1);
        if (pf) stB(u + 2, 0);
        MFMA16(4, 2, b1)
        if (pf) { stB(u + 2, 1); asm volatile("s_waitcnt vmcnt(4)" ::: "memory"); }
        else    { asm volatile("s_waitcnt vmcnt(0)" ::: "memory"); }
        MFMA16(4, 0, b0)
        RA2(1, 0); RB2(1, 0, b0);
        if (pf) stA(u + 2, 0);
        MFMA16(0, 0, b0)
        RB2(1, 1, b1);
        if (pf) stA(u + 2, 1);
        MFMA16(0, 2, b1)
        RA2(1, 1);
        if (pf) stB(u + 3, 0);
        MFMA16(4, 2, b1)
        if (pf) { stB(u + 3, 1); asm volatile("s_waitcnt vmcnt(4)" ::: "memory"); }
        else    { asm volatile("s_waitcnt vmcnt(0)" ::: "memory"); }
        MFMA16(4, 0, b0)
    }

    const int NH = N >> 1;
    #pragma unroll
    for (int mf = 0; mf < 8; ++mf)
      #pragma unroll
      for (int nf = 0; nf < 4; ++nf)
        #pragma unroll
        for (int r = 0; r < 4; ++r) {
            const int grow = bm * 256 + wr * 128 + mf * 16 + lk * 4 + r;
            const int gcol = bn * 256 + wc * 64 + nf * 16 + lm;
            const float v = acc[mf][nf][r];
            if constexpr (EPI == 5) {
                outp[(long)grow * 2048 + gcol] = to_bf16s(v);
            } else {   // EPI 6: SwiGLU pair via lane-xor
                const float g3 = __shfl_xor(v, 1);
                if (!(lane & 1)) {
                    const float sws = v / (1.f + __expf(-v));
                    outp[(long)grow * NH + (gcol >> 1)] = to_bf16s(sws * g3);
                }
            }
        }
}

// ---------------------------------------------------------------------------
// gemm128T: 128x128 tile, BK=64, 256 threads (4 waves 2x2, wave 64x64),
// 64 KiB LDS dbuf -> 2 blocks/CU.  Plain stage->read->MFMA->syncthreads loop,
// swizzled LDS, XCD chunking.  (round-7 verified)
// EPI 2: fp32 out = res + C.     EPI 8: bf16 transposed out vT[gcol][8192].
// ---------------------------------------------------------------------------
template<int EPI>
__global__ __launch_bounds__(256, 2)
void gemm128T(const short* __restrict__ A, const short* __restrict__ B0,
              const float* __restrict__ res, float* __restrict__ outp,
              short* __restrict__ outp2, int M, int N, int K) {
    __shared__ __align__(16) char lds[65536];   // A: 2x16K @0, B: 2x16K @32768

    const int t = threadIdx.x;
    const int lane = t & 63, w = t >> 6;
    const int wr = w >> 1, wc = w & 1;
    const int lm = lane & 15, lk = lane >> 4;
    const int sw = (lm & 7) << 4;

    const int nbn = N >> 7;
    const int chunk = gridDim.x >> 3;
    const int logical = (blockIdx.x & 7) * chunk + (blockIdx.x >> 3);
    const int bm = logical / nbn, bn = logical - (logical / nbn) * nbn;

    const long Kb = (long)K * 2;
    const char* Ab = (const char*)A;
    const char* Bb = (const char*)B0;

    long srcA[4], srcB[4];
    {
        const int rowp = t >> 3;                 // + c*32
        const int cbx = (t & 7) * 16;
        const int swz = ((t >> 3) & 7) << 4;
        #pragma unroll
        for (int c = 0; c < 4; ++c) {
            srcA[c] = (long)(bm * 128 + c * 32 + rowp) * Kb + (cbx ^ swz);
            srcB[c] = (long)(bn * 128 + c * 32 + rowp) * Kb + (cbx ^ swz);
        }
    }
    auto stage = [&](int kt, int buf) {
        #pragma unroll
        for (int c = 0; c < 4; ++c)
            load_lds16(Ab + srcA[c] + (long)kt * 128,
                       &lds[buf * 16384 + c * 4096 + t * 16]);
        #pragma unroll
        for (int c = 0; c < 4; ++c)
            load_lds16(Bb + srcB[c] + (long)kt * 128,
                       &lds[32768 + buf * 16384 + c * 4096 + t * 16]);
    };

    f32x4 acc[4][4] = {};
    const int nt = K >> 6;

    stage(0, 0);
    asm volatile("s_waitcnt vmcnt(0)" ::: "memory");
    __syncthreads();

    for (int kt = 0; kt < nt; ++kt) {
        const int buf = kt & 1;
        if (kt + 1 < nt) stage(kt + 1, buf ^ 1);
        bf16x8 a[4][2], b[4][2];
        #pragma unroll
        for (int m = 0; m < 4; ++m) {
            const int rb = buf * 16384 + (wr * 64 + m * 16 + lm) * 128;
            a[m][0] = *(const bf16x8*)&lds[rb + ((lk * 16) ^ sw)];
            a[m][1] = *(const bf16x8*)&lds[rb + ((64 + lk * 16) ^ sw)];
        }
        #pragma unroll
        for (int n = 0; n < 4; ++n) {
            const int rb = 32768 + buf * 16384 + (wc * 64 + n * 16 + lm) * 128;
            b[n][0] = *(const bf16x8*)&lds[rb + ((lk * 16) ^ sw)];
            b[n][1] = *(const bf16x8*)&lds[rb + ((64 + lk * 16) ^ sw)];
        }
        #pragma unroll
        for (int m = 0; m < 4; ++m)
            #pragma unroll
            for (int n = 0; n < 4; ++n) {
                acc[m][n] = __builtin_amdgcn_mfma_f32_16x16x32_bf16(a[m][0], b[n][0], acc[m][n], 0, 0, 0);
                acc[m][n] = __builtin_amdgcn_mfma_f32_16x16x32_bf16(a[m][1], b[n][1], acc[m][n], 0, 0, 0);
            }
        __syncthreads();
    }

    #pragma unroll
    for (int m = 0; m < 4; ++m)
      #pragma unroll
      for (int n = 0; n < 4; ++n)
        #pragma unroll
        for (int r = 0; r < 4; ++r) {
            const int grow = bm * 128 + wr * 64 + m * 16 + lk * 4 + r;
            const int gcol = bn * 128 + wc * 64 + n * 16 + lm;
            if constexpr (EPI == 2) {
                const long i = (long)grow * N + gcol;
                outp[i] = res[i] + acc[m][n][r];
            } else {  // EPI 8: transposed bf16 (V^T)
                outp2[(long)gcol * 8192 + grow] = to_bf16s(acc[m][n][r]);
            }
        }
}

// ---------------------------------------------------------------------------
// Windowed causal attention (verified): dbuf staging, 32 q/block.
// ---------------------------------------------------------------------------
__global__ __launch_bounds__(128)
void attn_kernel(const short* __restrict__ Q, const short* __restrict__ Km,
                 int ldq, const short* __restrict__ VT, short* __restrict__ att) {
    const int T = 2048, D = 1024, Mtot = 8192;
    const int bid = blockIdx.x;
    const int b = bid >> 6;
    const int q0 = (bid & 63) << 5;
    const long qrow0 = (long)b * T + q0;
    const int t = threadIdx.x, lane = t & 63, w = t >> 6;

    __shared__ short Qs[2][32 * 32];
    __shared__ short Ks[2][96 * 32];
    __shared__ float S_lds[32][100];
    __shared__ short P_lds[32 * 96];
    __shared__ short VTs[2][128 * 96];

    const int trow = t >> 2, tk8 = (t & 3) * 8;
    auto stageQK = [&](int kt, int bf) {
        const int k0 = kt << 5;
        load_lds16(Q + (qrow0 + trow) * ldq + k0 + tk8, &Qs[bf][t * 8]);
        #pragma unroll
        for (int s2 = 0; s2 < 3; ++s2) {
            const int krow = s2 * 32 + trow;
            int j = q0 - 64 + krow; if (j < 0) j = 0;
            load_lds16(Km + ((long)b * T + j) * ldq + k0 + tk8, &Ks[bf][(s2 * 128 + t) * 8]);
        }
    };

    f32x4 s[6] = {};
    stageQK(0, 0);
    __syncthreads();
    for (int kt = 0; kt < 32; ++kt) {
        const int cb = kt & 1;
        if (kt + 1 < 32) stageQK(kt + 1, cb ^ 1);
        const int ko = (lane >> 4) * 8;
        const bf16x8 aq = *(const bf16x8*)&Qs[cb][(w * 16 + (lane & 15)) * 32 + ko];
        #pragma unroll
        for (int n = 0; n < 6; ++n) {
            const bf16x8 bk = *(const bf16x8*)&Ks[cb][(n * 16 + (lane & 15)) * 32 + ko];
            s[n] = __builtin_amdgcn_mfma_f32_16x16x32_bf16(aq, bk, s[n], 0, 0, 0);
        }
        __syncthreads();
    }
    #pragma unroll
    for (int n = 0; n < 6; ++n)
        #pragma unroll
        for (int r = 0; r < 4; ++r)
            S_lds[w * 16 + ((lane >> 4) << 2) + r][n * 16 + (lane & 15)] = s[n][r] * 0.03125f;
    __syncthreads();

    {
        const int row = t >> 2, c0 = (t & 3) * 24;
        float e[24];
        float mx = -1e30f;
        #pragma unroll
        for (int c = 0; c < 24; ++c) {
            const int kj = c0 + c;
            const bool valid = (kj > row) && (kj <= row + 64) && (q0 - 64 + kj >= 0);
            const float sv = valid ? S_lds[row][kj] : -1e30f;
            e[c] = sv;
            mx = fmaxf(mx, sv);
        }
        mx = fmaxf(mx, __shfl_xor(mx, 1));
        mx = fmaxf(mx, __shfl_xor(mx, 2));
        float sum = 0.f;
        #pragma unroll
        for (int c = 0; c < 24; ++c) {
            const float ev = (e[c] > -1e29f) ? __expf(e[c] - mx) : 0.f;
            e[c] = ev; sum += ev;
        }
        sum += __shfl_xor(sum, 1);
        sum += __shfl_xor(sum, 2);
        const float inv = 1.f / sum;
        #pragma unroll
        for (int c = 0; c < 24; ++c)
            P_lds[row * 96 + c0 + c] = to_bf16s(e[c] * inv);
    }

    auto stageV = [&](int dc, int bf) {
        #pragma unroll
        for (int s2 = 0; s2 < 12; ++s2) {
            const int idx = s2 * 128 + t;
            const int dr = idx / 12, c = idx - dr * 12;
            int j = q0 - 64 + c * 8; if (j < 0) j = 0;
            load_lds16(VT + (long)(dc * 128 + dr) * Mtot + b * T + j, &VTs[bf][idx * 8]);
        }
    };
    stageV(0, 0);
    __syncthreads();

    bf16x8 pa[3];
    {
        const int ko = (lane >> 4) * 8;
        #pragma unroll
        for (int kc = 0; kc < 3; ++kc)
            pa[kc] = *(const bf16x8*)&P_lds[(w * 16 + (lane & 15)) * 96 + kc * 32 + ko];
    }
    for (int dc = 0; dc < 8; ++dc) {
        const int cb = dc & 1;
        if (dc + 1 < 8) stageV(dc + 1, cb ^ 1);
        f32x4 o[8] = {};
        const int ko = (lane >> 4) * 8;
        #pragma unroll
        for (int kc = 0; kc < 3; ++kc)
            #pragma unroll
            for (int n = 0; n < 8; ++n) {
                const bf16x8 vb = *(const bf16x8*)&VTs[cb][(n * 16 + (lane & 15)) * 96 + kc * 32 + ko];
                o[n] = __builtin_amdgcn_mfma_f32_16x16x32_bf16(pa[kc], vb, o[n], 0, 0, 0);
            }
        __syncthreads();
        #pragma unroll
        for (int n = 0; n < 8; ++n)
            #pragma unroll
            for (int r = 0; r < 4; ++r) {
                const long grow = qrow0 + w * 16 + ((lane >> 4) << 2) + r;
                const int gcol = dc * 128 + n * 16 + (lane & 15);
                att[grow * D + gcol] = to_bf16s(o[n][r]);
            }
    }
}

// ---------------------------------------------------------------------------
extern "C" void kernel_launch(void* const* d_in, const int* in_sizes, int n_in,
                              void* d_out, int out_size, void* d_ws, size_t ws_size,
                              hipStream_t stream) {
    const float* x   = (const float*)d_in[0];
    const float* n1w = (const float*)d_in[1];
    const float* n2w = (const float*)d_in[2];
    const float* Wq  = (const float*)d_in[3];
    const float* Wk  = (const float*)d_in[4];
    const float* Wv  = (const float*)d_in[5];
    const float* Wo  = (const float*)d_in[6];
    const float* W1  = (const float*)d_in[7];
    const float* W2  = (const float*)d_in[8];
    const float* W3  = (const float*)d_in[9];

    const int M = 8192;           // B*T
    char* ws = (char*)d_ws;
    size_t off = 0;
    auto alloc = [&](size_t bytes) { void* p = ws + off; off += (bytes + 255) & ~(size_t)255; return p; };

    short* xn1 = (short*)alloc((size_t)M * 1024 * 2);   // reused as att
    short* qk  = (short*)alloc((size_t)M * 2048 * 2);   // q | k rows (ld=2048); xn2/h alias
    short* vT  = (short*)alloc((size_t)M * 1024 * 2);   // V^T [1024][8192]
    float* x2  = (float*)alloc((size_t)M * 1024 * 4);
    short* WqT = (short*)alloc((size_t)1024 * 1024 * 2);   // WqT,WkT contiguous = QK weight
    short* WkT = (short*)alloc((size_t)1024 * 1024 * 2);
    short* WvT = (short*)alloc((size_t)1024 * 1024 * 2);
    short* WoT = (short*)alloc((size_t)1024 * 1024 * 2);
    short* W13T= (short*)alloc((size_t)4096 * 1024 * 2);   // interleaved W1/W3
    short* W2T = (short*)alloc((size_t)1024 * 2048 * 2);
    short* att = xn1;                                   // xn1 dead after QKV
    short* xn2 = qk;                                    // q/k dead after attention
    short* h   = qk + (size_t)M * 1024;                 // spans qk 2nd half + vT (32MB)

    // transposes + rmsnorm1 in one launch
    prep_kernel<<<18432, 256, 0, stream>>>(Wq, Wk, Wv, Wo, W1, W3, W2,
                                           WqT, WkT, WvT, WoT, W13T, W2T,
                                           x, n1w, xn1);
    // QK: [M,2048] on the 8-phase 256^2 structure, grid 256 = exactly 1 round
    gemm256T<5><<<256, 512, 0, stream>>>(xn1, WqT, qk, M, 2048, 1024);
    // V^T: [M,1024] transposed out on the 2-blocks/CU 128^2 structure, grid 512
    gemm128T<8><<<512, 256, 0, stream>>>(xn1, WvT, nullptr, nullptr, vT, M, 1024, 1024);
    // attention -> att (bf16)
    attn_kernel<<<256, 128, 0, stream>>>(qk, qk + 1024, 2048, vT, att);
    // x2 = x + att @ Wo   (fp32)
    gemm128T<2><<<512, 256, 0, stream>>>(att, WoT, x, x2, nullptr, M, 1024, 1024);
    // norm2 -> xn2 (bf16)
    rmsnorm_kernel<<<M, 256, 0, stream>>>(x2, n2w, xn2);
    // h = silu(xn2@W1) * (xn2@W3)  — fused interleaved GEMM, N=4096, grid 512
    gemm256T<6><<<512, 512, 0, stream>>>(xn2, W13T, h, M, 4096, 1024);
    // out = x2 + h @ W2   (fp32)
    gemm128T<2><<<512, 256, 0, stream>>>(h, W2T, x2, (float*)d_out, nullptr, M, 1024, 2048);
}

// Round 13
// 267.012 us; speedup vs baseline: 1.1624x; 1.0185x over previous
//
#include <hip/hip_runtime.h>
#include <hip/hip_bf16.h>

typedef __attribute__((ext_vector_type(8))) short bf16x8;
typedef __attribute__((ext_vector_type(4))) float f32x4;

__device__ __forceinline__ short to_bf16s(float f) {
    union { __hip_bfloat16 h; short s; } u;
    u.h = __float2bfloat16(f);
    return u.s;
}

__device__ __forceinline__ float bf16s_to_f(short s) {
    union { float f; unsigned u; } cv;
    cv.u = ((unsigned)(unsigned short)s) << 16;
    return cv.f;
}

__device__ __forceinline__ void load_lds16(const void* g, void* l) {
    __builtin_amdgcn_global_load_lds((const __attribute__((address_space(1))) void*)g,
                                     (__attribute__((address_space(3))) void*)l, 16, 0, 0);
}

// ---------------------------------------------------------------------------
// prep: blocks [0,10240): weight transposes (fp32 [K][N] -> bf16 [N][K]),
// W1/W3 column-interleaved into W13T[4096][1024].  Blocks [10240,18432):
// rmsnorm1 row (bid-10240) -> xn1 bf16.
// ---------------------------------------------------------------------------
__global__ __launch_bounds__(256)
void prep_kernel(const float* __restrict__ Wq, const float* __restrict__ Wk,
                 const float* __restrict__ Wv, const float* __restrict__ Wo,
                 const float* __restrict__ W1, const float* __restrict__ W3,
                 const float* __restrict__ W2,
                 short* __restrict__ WqT, short* __restrict__ WkT,
                 short* __restrict__ WvT, short* __restrict__ WoT,
                 short* __restrict__ W13T, short* __restrict__ W2T,
                 const float* __restrict__ x, const float* __restrict__ n1w,
                 short* __restrict__ xn1) {
    const int bid = blockIdx.x;
    const int t = threadIdx.x;
    if (bid >= 10240) {
        const long row = bid - 10240;
        float4 v = ((const float4*)(x + row * 1024))[t];
        float ss = v.x * v.x + v.y * v.y + v.z * v.z + v.w * v.w;
        #pragma unroll
        for (int off = 32; off; off >>= 1) ss += __shfl_xor(ss, off);
        __shared__ float red[4];
        if ((t & 63) == 0) red[t >> 6] = ss;
        __syncthreads();
        ss = red[0] + red[1] + red[2] + red[3];
        const float inv = rsqrtf(ss * (1.0f / 1024.0f) + 1e-6f);
        float4 wv = ((const float4*)n1w)[t];
        short4 o;
        o.x = to_bf16s(v.x * inv * wv.x);
        o.y = to_bf16s(v.y * inv * wv.y);
        o.z = to_bf16s(v.z * inv * wv.z);
        o.w = to_bf16s(v.w * inv * wv.w);
        *(short4*)&xn1[row * 1024 + t * 4] = o;
        return;
    }
    __shared__ float tile[32][33];
    const float* src; short* dst; int K, N, tl, rs = 1, ro = 0;
    if (bid < 4096) {
        const int wi = bid >> 10; tl = bid & 1023;
        src = wi == 0 ? Wq : wi == 1 ? Wk : wi == 2 ? Wv : Wo;
        dst = wi == 0 ? WqT : wi == 1 ? WkT : wi == 2 ? WvT : WoT;
        K = 1024; N = 1024;
    } else if (bid < 8192) {
        const int wi = (bid - 4096) >> 11; tl = (bid - 4096) & 2047;
        src = wi ? W3 : W1; dst = W13T; rs = 2; ro = wi;
        K = 1024; N = 2048;
    } else {
        tl = bid - 8192; src = W2; dst = W2T;
        K = 2048; N = 1024;
    }
    const int nx = N >> 5;
    const int n0 = (tl % nx) * 32, k0 = (tl / nx) * 32;
    {
        const int lr = t >> 3, lc = (t & 7) * 4;
        float4 v = *(const float4*)&src[(long)(k0 + lr) * N + n0 + lc];
        tile[lr][lc] = v.x; tile[lr][lc + 1] = v.y;
        tile[lr][lc + 2] = v.z; tile[lr][lc + 3] = v.w;
    }
    __syncthreads();
    {
        const int nr = t >> 3, kc = (t & 7) * 4;
        short4 o;
        o.x = to_bf16s(tile[kc][nr]);
        o.y = to_bf16s(tile[kc + 1][nr]);
        o.z = to_bf16s(tile[kc + 2][nr]);
        o.w = to_bf16s(tile[kc + 3][nr]);
        *(short4*)&dst[(long)((n0 + nr) * rs + ro) * K + k0 + kc] = o;
    }
}

// ---------------------------------------------------------------------------
// RMSNorm (bf16 in) -> bf16 out.  One block per row, D=1024.  (norm2)
// ---------------------------------------------------------------------------
__global__ __launch_bounds__(256)
void rmsnorm_bf16(const short* __restrict__ xb, const float* __restrict__ wt,
                  short* __restrict__ out) {
    const long row = blockIdx.x;
    const int t = threadIdx.x;
    short4 sv = ((const short4*)(xb + row * 1024))[t];
    float v0 = bf16s_to_f(sv.x), v1 = bf16s_to_f(sv.y);
    float v2 = bf16s_to_f(sv.z), v3 = bf16s_to_f(sv.w);
    float ss = v0 * v0 + v1 * v1 + v2 * v2 + v3 * v3;
    #pragma unroll
    for (int off = 32; off; off >>= 1) ss += __shfl_xor(ss, off);
    __shared__ float red[4];
    if ((t & 63) == 0) red[t >> 6] = ss;
    __syncthreads();
    ss = red[0] + red[1] + red[2] + red[3];
    const float inv = rsqrtf(ss * (1.0f / 1024.0f) + 1e-6f);
    float4 wv = ((const float4*)wt)[t];
    short4 o;
    o.x = to_bf16s(v0 * inv * wv.x);
    o.y = to_bf16s(v1 * inv * wv.y);
    o.z = to_bf16s(v2 * inv * wv.z);
    o.w = to_bf16s(v3 * inv * wv.w);
    *(short4*)&out[row * 1024 + t * 4] = o;
}

// ---------------------------------------------------------------------------
// MFMA phase macro (barrier ; lgkm ; setprio ; 16 MFMA ; barrier).
// ---------------------------------------------------------------------------
#define MFMA16(MB, NB, BREG)                                                   \
    __builtin_amdgcn_s_barrier();                                              \
    asm volatile("s_waitcnt lgkmcnt(0)");                                      \
    __builtin_amdgcn_s_setprio(1);                                             \
    _Pragma("unroll")                                                          \
    for (int m_ = 0; m_ < 4; ++m_)                                             \
        _Pragma("unroll")                                                      \
        for (int n_ = 0; n_ < 2; ++n_) {                                       \
            acc[(MB) + m_][(NB) + n_] = __builtin_amdgcn_mfma_f32_16x16x32_bf16( \
                a[m_][0], BREG[n_][0], acc[(MB) + m_][(NB) + n_], 0, 0, 0);    \
            acc[(MB) + m_][(NB) + n_] = __builtin_amdgcn_mfma_f32_16x16x32_bf16( \
                a[m_][1], BREG[n_][1], acc[(MB) + m_][(NB) + n_], 0, 0, 0);    \
        }                                                                      \
    __builtin_amdgcn_s_setprio(0);                                             \
    __builtin_amdgcn_s_barrier();

// ---------------------------------------------------------------------------
// gemm256T: 256x256 tile, BK=64, 8 waves (2x4) of 128x64, 2-buf dbuf (128K),
// m201-style 8-phase schedule, vmcnt(4) checkpoints (verified @758TF).
// EPI 5: bf16 outp[row][2048] (ld 2048) — used for QK (N=2048).
// EPI 6: fused SwiGLU over column-interleaved B (even gcol = W1 col, odd =
//        W3 col): outp[row][gcol/2] = silu(C_even) * C_odd.
// ---------------------------------------------------------------------------
#define RA2(BUF, MG)                                                           \
    _Pragma("unroll")                                                          \
    for (int m_ = 0; m_ < 4; ++m_) {                                           \
        const int rb_ = ((BUF) * 2 + wr) * 16384 + (((MG) * 4 + m_) * 16 + lm) * 128; \
        a[m_][0] = *(const bf16x8*)&lds[rb_ + ((lk * 16) ^ sw)];               \
        a[m_][1] = *(const bf16x8*)&lds[rb_ + ((64 + lk * 16) ^ sw)];          \
    }
#define RB2(BUF, NH, ARR)                                                      \
    _Pragma("unroll")                                                          \
    for (int n_ = 0; n_ < 2; ++n_) {                                           \
        const int rb_ = 65536 + ((BUF) * 2 + (wc >> 1)) * 16384 +              \
                        ((wc & 1) * 64 + ((NH) * 2 + n_) * 16 + lm) * 128;     \
        ARR[n_][0] = *(const bf16x8*)&lds[rb_ + ((lk * 16) ^ sw)];             \
        ARR[n_][1] = *(const bf16x8*)&lds[rb_ + ((64 + lk * 16) ^ sw)];        \
    }

template<int EPI>
__global__ __launch_bounds__(512, 2)
void gemm256T(const short* __restrict__ A, const short* __restrict__ B0,
              short* __restrict__ outp, int M, int N, int K) {
    __shared__ __align__(16) char lds[131072];

    const int t = threadIdx.x;
    const int lane = t & 63, w = t >> 6;
    const int wr = w >> 2, wc = w & 3;
    const int lm = lane & 15, lk = lane >> 4;
    const int sw = (lm & 7) << 4;

    const int nbn = N >> 8;
    const int chunk = gridDim.x >> 3;
    const int logical = (blockIdx.x & 7) * chunk + (blockIdx.x >> 3);
    const int bm = logical / nbn, bn = logical - (logical / nbn) * nbn;

    const long Kb = (long)K * 2;
    const char* Ab = (const char*)A;
    const char* Bb = (const char*)B0;

    long srcA[2][2], srcB[2][2];
    {
        const int rowp = t >> 3;
        const int cbx = (t & 7) * 16;
        const int swz = ((t >> 3) & 7) << 4;
        #pragma unroll
        for (int h = 0; h < 2; ++h)
            #pragma unroll
            for (int c = 0; c < 2; ++c) {
                srcA[h][c] = (long)(bm * 256 + h * 128 + c * 64 + rowp) * Kb + (cbx ^ swz);
                srcB[h][c] = (long)(bn * 256 + h * 128 + c * 64 + rowp) * Kb + (cbx ^ swz);
            }
    }
    auto stA = [&](int kt, int h) {
        const int buf = kt & 1;
        #pragma unroll
        for (int c = 0; c < 2; ++c)
            load_lds16(Ab + srcA[h][c] + (long)kt * 128,
                       &lds[(buf * 2 + h) * 16384 + c * 8192 + t * 16]);
    };
    auto stB = [&](int kt, int h) {
        const int buf = kt & 1;
        #pragma unroll
        for (int c = 0; c < 2; ++c)
            load_lds16(Bb + srcB[h][c] + (long)kt * 128,
                       &lds[65536 + (buf * 2 + h) * 16384 + c * 8192 + t * 16]);
    };

    f32x4 acc[8][4] = {};
    bf16x8 a[4][2], b0[2][2], b1[2][2];
    const int nt = K >> 6;

    stB(0, 0); stB(0, 1); stA(0, 0); stA(0, 1); stB(1, 0); stB(1, 1);
    asm volatile("s_waitcnt vmcnt(4)" ::: "memory");
    __builtin_amdgcn_s_barrier();

    for (int u = 0; u < nt; u += 2) {
        const bool pf = (u + 2) < nt;
        RA2(0, 0); RB2(0, 0, b0);
        stA(u + 1, 0);
        MFMA16(0, 0, b0)
        RB2(0, 1, b1);
        stA(u + 1, 1);
        MFMA16(0, 2, b1)
        RA2(0, 1);
        if (pf) stB(u + 2, 0);
        MFMA16(4, 2, b1)
        if (pf) { stB(u + 2, 1); asm volatile("s_waitcnt vmcnt(4)" ::: "memory"); }
        else    { asm volatile("s_waitcnt vmcnt(0)" ::: "memory"); }
        MFMA16(4, 0, b0)
        RA2(1, 0); RB2(1, 0, b0);
        if (pf) stA(u + 2, 0);
        MFMA16(0, 0, b0)
        RB2(1, 1, b1);
        if (pf) stA(u + 2, 1);
        MFMA16(0, 2, b1)
        RA2(1, 1);
        if (pf) stB(u + 3, 0);
        MFMA16(4, 2, b1)
        if (pf) { stB(u + 3, 1); asm volatile("s_waitcnt vmcnt(4)" ::: "memory"); }
        else    { asm volatile("s_waitcnt vmcnt(0)" ::: "memory"); }
        MFMA16(4, 0, b0)
    }

    const int NH = N >> 1;
    #pragma unroll
    for (int mf = 0; mf < 8; ++mf)
      #pragma unroll
      for (int nf = 0; nf < 4; ++nf)
        #pragma unroll
        for (int r = 0; r < 4; ++r) {
            const int grow = bm * 256 + wr * 128 + mf * 16 + lk * 4 + r;
            const int gcol = bn * 256 + wc * 64 + nf * 16 + lm;
            const float v = acc[mf][nf][r];
            if constexpr (EPI == 5) {
                outp[(long)grow * 2048 + gcol] = to_bf16s(v);
            } else {   // EPI 6: SwiGLU pair via lane-xor
                const float g3 = __shfl_xor(v, 1);
                if (!(lane & 1)) {
                    const float sws = v / (1.f + __expf(-v));
                    outp[(long)grow * NH + (gcol >> 1)] = to_bf16s(sws * g3);
                }
            }
        }
}

// ---------------------------------------------------------------------------
// gemm128T: 128x128 tile, BK=64, 256 threads (4 waves 2x2, wave 64x64),
// 64 KiB LDS dbuf -> 2 blocks/CU.  Plain stage->read->MFMA->syncthreads loop,
// swizzled LDS, XCD chunking.  (verified)
// EPI 3: bf16 resout[i] = to_bf16(res_f32[i] + C)      (Wo: x2b = x + attWo)
// EPI 8: bf16 transposed out outp2[gcol][8192]          (V^T)
// EPI 9: fp32 outp[i] = bf16(resb[i]) + C               (W2: out = x2b + h W2)
// ---------------------------------------------------------------------------
template<int EPI>
__global__ __launch_bounds__(256, 2)
void gemm128T(const short* __restrict__ A, const short* __restrict__ B0,
              const float* __restrict__ res, float* __restrict__ outp,
              short* __restrict__ outp2, int M, int N, int K) {
    __shared__ __align__(16) char lds[65536];   // A: 2x16K @0, B: 2x16K @32768

    const int t = threadIdx.x;
    const int lane = t & 63, w = t >> 6;
    const int wr = w >> 1, wc = w & 1;
    const int lm = lane & 15, lk = lane >> 4;
    const int sw = (lm & 7) << 4;

    const int nbn = N >> 7;
    const int chunk = gridDim.x >> 3;
    const int logical = (blockIdx.x & 7) * chunk + (blockIdx.x >> 3);
    const int bm = logical / nbn, bn = logical - (logical / nbn) * nbn;

    const long Kb = (long)K * 2;
    const char* Ab = (const char*)A;
    const char* Bb = (const char*)B0;

    long srcA[4], srcB[4];
    {
        const int rowp = t >> 3;                 // + c*32
        const int cbx = (t & 7) * 16;
        const int swz = ((t >> 3) & 7) << 4;
        #pragma unroll
        for (int c = 0; c < 4; ++c) {
            srcA[c] = (long)(bm * 128 + c * 32 + rowp) * Kb + (cbx ^ swz);
            srcB[c] = (long)(bn * 128 + c * 32 + rowp) * Kb + (cbx ^ swz);
        }
    }
    auto stage = [&](int kt, int buf) {
        #pragma unroll
        for (int c = 0; c < 4; ++c)
            load_lds16(Ab + srcA[c] + (long)kt * 128,
                       &lds[buf * 16384 + c * 4096 + t * 16]);
        #pragma unroll
        for (int c = 0; c < 4; ++c)
            load_lds16(Bb + srcB[c] + (long)kt * 128,
                       &lds[32768 + buf * 16384 + c * 4096 + t * 16]);
    };

    f32x4 acc[4][4] = {};
    const int nt = K >> 6;

    stage(0, 0);
    asm volatile("s_waitcnt vmcnt(0)" ::: "memory");
    __syncthreads();

    for (int kt = 0; kt < nt; ++kt) {
        const int buf = kt & 1;
        if (kt + 1 < nt) stage(kt + 1, buf ^ 1);
        bf16x8 a[4][2], b[4][2];
        #pragma unroll
        for (int m = 0; m < 4; ++m) {
            const int rb = buf * 16384 + (wr * 64 + m * 16 + lm) * 128;
            a[m][0] = *(const bf16x8*)&lds[rb + ((lk * 16) ^ sw)];
            a[m][1] = *(const bf16x8*)&lds[rb + ((64 + lk * 16) ^ sw)];
        }
        #pragma unroll
        for (int n = 0; n < 4; ++n) {
            const int rb = 32768 + buf * 16384 + (wc * 64 + n * 16 + lm) * 128;
            b[n][0] = *(const bf16x8*)&lds[rb + ((lk * 16) ^ sw)];
            b[n][1] = *(const bf16x8*)&lds[rb + ((64 + lk * 16) ^ sw)];
        }
        #pragma unroll
        for (int m = 0; m < 4; ++m)
            #pragma unroll
            for (int n = 0; n < 4; ++n) {
                acc[m][n] = __builtin_amdgcn_mfma_f32_16x16x32_bf16(a[m][0], b[n][0], acc[m][n], 0, 0, 0);
                acc[m][n] = __builtin_amdgcn_mfma_f32_16x16x32_bf16(a[m][1], b[n][1], acc[m][n], 0, 0, 0);
            }
        __syncthreads();
    }

    #pragma unroll
    for (int m = 0; m < 4; ++m)
      #pragma unroll
      for (int n = 0; n < 4; ++n)
        #pragma unroll
        for (int r = 0; r < 4; ++r) {
            const int grow = bm * 128 + wr * 64 + m * 16 + lk * 4 + r;
            const int gcol = bn * 128 + wc * 64 + n * 16 + lm;
            if constexpr (EPI == 3) {
                const long i = (long)grow * N + gcol;
                outp2[i] = to_bf16s(res[i] + acc[m][n][r]);
            } else if constexpr (EPI == 8) {
                outp2[(long)gcol * 8192 + grow] = to_bf16s(acc[m][n][r]);
            } else {  // EPI 9
                const long i = (long)grow * N + gcol;
                outp[i] = bf16s_to_f(outp2[i]) + acc[m][n][r];
            }
        }
}

// ---------------------------------------------------------------------------
// Windowed causal attention (verified): dbuf staging, 32 q/block.
// ---------------------------------------------------------------------------
__global__ __launch_bounds__(128)
void attn_kernel(const short* __restrict__ Q, const short* __restrict__ Km,
                 int ldq, const short* __restrict__ VT, short* __restrict__ att) {
    const int T = 2048, D = 1024, Mtot = 8192;
    const int bid = blockIdx.x;
    const int b = bid >> 6;
    const int q0 = (bid & 63) << 5;
    const long qrow0 = (long)b * T + q0;
    const int t = threadIdx.x, lane = t & 63, w = t >> 6;

    __shared__ short Qs[2][32 * 32];
    __shared__ short Ks[2][96 * 32];
    __shared__ float S_lds[32][100];
    __shared__ short P_lds[32 * 96];
    __shared__ short VTs[2][128 * 96];

    const int trow = t >> 2, tk8 = (t & 3) * 8;
    auto stageQK = [&](int kt, int bf) {
        const int k0 = kt << 5;
        load_lds16(Q + (qrow0 + trow) * ldq + k0 + tk8, &Qs[bf][t * 8]);
        #pragma unroll
        for (int s2 = 0; s2 < 3; ++s2) {
            const int krow = s2 * 32 + trow;
            int j = q0 - 64 + krow; if (j < 0) j = 0;
            load_lds16(Km + ((long)b * T + j) * ldq + k0 + tk8, &Ks[bf][(s2 * 128 + t) * 8]);
        }
    };

    f32x4 s[6] = {};
    stageQK(0, 0);
    __syncthreads();
    for (int kt = 0; kt < 32; ++kt) {
        const int cb = kt & 1;
        if (kt + 1 < 32) stageQK(kt + 1, cb ^ 1);
        const int ko = (lane >> 4) * 8;
        const bf16x8 aq = *(const bf16x8*)&Qs[cb][(w * 16 + (lane & 15)) * 32 + ko];
        #pragma unroll
        for (int n = 0; n < 6; ++n) {
            const bf16x8 bk = *(const bf16x8*)&Ks[cb][(n * 16 + (lane & 15)) * 32 + ko];
            s[n] = __builtin_amdgcn_mfma_f32_16x16x32_bf16(aq, bk, s[n], 0, 0, 0);
        }
        __syncthreads();
    }
    #pragma unroll
    for (int n = 0; n < 6; ++n)
        #pragma unroll
        for (int r = 0; r < 4; ++r)
            S_lds[w * 16 + ((lane >> 4) << 2) + r][n * 16 + (lane & 15)] = s[n][r] * 0.03125f;
    __syncthreads();

    {
        const int row = t >> 2, c0 = (t & 3) * 24;
        float e[24];
        float mx = -1e30f;
        #pragma unroll
        for (int c = 0; c < 24; ++c) {
            const int kj = c0 + c;
            const bool valid = (kj > row) && (kj <= row + 64) && (q0 - 64 + kj >= 0);
            const float sv = valid ? S_lds[row][kj] : -1e30f;
            e[c] = sv;
            mx = fmaxf(mx, sv);
        }
        mx = fmaxf(mx, __shfl_xor(mx, 1));
        mx = fmaxf(mx, __shfl_xor(mx, 2));
        float sum = 0.f;
        #pragma unroll
        for (int c = 0; c < 24; ++c) {
            const float ev = (e[c] > -1e29f) ? __expf(e[c] - mx) : 0.f;
            e[c] = ev; sum += ev;
        }
        sum += __shfl_xor(sum, 1);
        sum += __shfl_xor(sum, 2);
        const float inv = 1.f / sum;
        #pragma unroll
        for (int c = 0; c < 24; ++c)
            P_lds[row * 96 + c0 + c] = to_bf16s(e[c] * inv);
    }

    auto stageV = [&](int dc, int bf) {
        #pragma unroll
        for (int s2 = 0; s2 < 12; ++s2) {
            const int idx = s2 * 128 + t;
            const int dr = idx / 12, c = idx - dr * 12;
            int j = q0 - 64 + c * 8; if (j < 0) j = 0;
            load_lds16(VT + (long)(dc * 128 + dr) * Mtot + b * T + j, &VTs[bf][idx * 8]);
        }
    };
    stageV(0, 0);
    __syncthreads();

    bf16x8 pa[3];
    {
        const int ko = (lane >> 4) * 8;
        #pragma unroll
        for (int kc = 0; kc < 3; ++kc)
            pa[kc] = *(const bf16x8*)&P_lds[(w * 16 + (lane & 15)) * 96 + kc * 32 + ko];
    }
    for (int dc = 0; dc < 8; ++dc) {
        const int cb = dc & 1;
        if (dc + 1 < 8) stageV(dc + 1, cb ^ 1);
        f32x4 o[8] = {};
        const int ko = (lane >> 4) * 8;
        #pragma unroll
        for (int kc = 0; kc < 3; ++kc)
            #pragma unroll
            for (int n = 0; n < 8; ++n) {
                const bf16x8 vb = *(const bf16x8*)&VTs[cb][(n * 16 + (lane & 15)) * 96 + kc * 32 + ko];
                o[n] = __builtin_amdgcn_mfma_f32_16x16x32_bf16(pa[kc], vb, o[n], 0, 0, 0);
            }
        __syncthreads();
        #pragma unroll
        for (int n = 0; n < 8; ++n)
            #pragma unroll
            for (int r = 0; r < 4; ++r) {
                const long grow = qrow0 + w * 16 + ((lane >> 4) << 2) + r;
                const int gcol = dc * 128 + n * 16 + (lane & 15);
                att[grow * D + gcol] = to_bf16s(o[n][r]);
            }
    }
}

// ---------------------------------------------------------------------------
extern "C" void kernel_launch(void* const* d_in, const int* in_sizes, int n_in,
                              void* d_out, int out_size, void* d_ws, size_t ws_size,
                              hipStream_t stream) {
    const float* x   = (const float*)d_in[0];
    const float* n1w = (const float*)d_in[1];
    const float* n2w = (const float*)d_in[2];
    const float* Wq  = (const float*)d_in[3];
    const float* Wk  = (const float*)d_in[4];
    const float* Wv  = (const float*)d_in[5];
    const float* Wo  = (const float*)d_in[6];
    const float* W1  = (const float*)d_in[7];
    const float* W2  = (const float*)d_in[8];
    const float* W3  = (const float*)d_in[9];

    const int M = 8192;           // B*T
    char* ws = (char*)d_ws;
    size_t off = 0;
    auto alloc = [&](size_t bytes) { void* p = ws + off; off += (bytes + 255) & ~(size_t)255; return p; };

    short* xn1 = (short*)alloc((size_t)M * 1024 * 2);   // reused as att
    short* qk  = (short*)alloc((size_t)M * 2048 * 2);   // q | k rows (ld=2048); xn2/h alias
    short* vT  = (short*)alloc((size_t)M * 1024 * 2);   // V^T [1024][8192]
    short* x2b = (short*)alloc((size_t)M * 1024 * 2);   // bf16 residual x + attWo
    short* WqT = (short*)alloc((size_t)1024 * 1024 * 2);   // WqT,WkT contiguous = QK weight
    short* WkT = (short*)alloc((size_t)1024 * 1024 * 2);
    short* WvT = (short*)alloc((size_t)1024 * 1024 * 2);
    short* WoT = (short*)alloc((size_t)1024 * 1024 * 2);
    short* W13T= (short*)alloc((size_t)4096 * 1024 * 2);   // interleaved W1/W3
    short* W2T = (short*)alloc((size_t)1024 * 2048 * 2);
    short* att = xn1;                                   // xn1 dead after QKV
    short* xn2 = qk;                                    // q/k dead after attention
    short* h   = qk + (size_t)M * 1024;                 // spans qk 2nd half + vT (32MB)

    // transposes + rmsnorm1 in one launch
    prep_kernel<<<18432, 256, 0, stream>>>(Wq, Wk, Wv, Wo, W1, W3, W2,
                                           WqT, WkT, WvT, WoT, W13T, W2T,
                                           x, n1w, xn1);
    // QK: [M,2048] on the 8-phase 256^2 structure, grid 256 = exactly 1 round
    gemm256T<5><<<256, 512, 0, stream>>>(xn1, WqT, qk, M, 2048, 1024);
    // V^T: [M,1024] transposed out on the 2-blocks/CU 128^2 structure, grid 512
    gemm128T<8><<<512, 256, 0, stream>>>(xn1, WvT, nullptr, nullptr, vT, M, 1024, 1024);
    // attention -> att (bf16)
    attn_kernel<<<256, 128, 0, stream>>>(qk, qk + 1024, 2048, vT, att);
    // x2b = bf16(x + att @ Wo)
    gemm128T<3><<<512, 256, 0, stream>>>(att, WoT, x, nullptr, x2b, M, 1024, 1024);
    // norm2 (bf16 in) -> xn2 (bf16)
    rmsnorm_bf16<<<M, 256, 0, stream>>>(x2b, n2w, xn2);
    // h = silu(xn2@W1) * (xn2@W3)  — fused interleaved GEMM, N=4096, grid 512
    gemm256T<6><<<512, 512, 0, stream>>>(xn2, W13T, h, M, 4096, 1024);
    // out = x2b + h @ W2   (fp32)
    gemm128T<9><<<512, 256, 0, stream>>>(h, W2T, nullptr, (float*)d_out, x2b, M, 1024, 2048);
}